// Round 10
// baseline (1463.691 us; speedup 1.0000x reference)
//
#include <hip/hip_runtime.h>
#include <hip/hip_bf16.h>

#define DD 1024
#define SS 1024
#define BB 2
#define HH 16
#define DFFN 4096
#define LLAYERS 2
#define RSTEPS 3
#define VV 32000
#define NTOK (BB*SS)

typedef __attribute__((ext_vector_type(8))) short s16x8;
typedef __attribute__((ext_vector_type(8))) __bf16 bf16x8;
typedef __attribute__((ext_vector_type(4))) float f32x4;

__device__ __forceinline__ unsigned short f2bf(float f) {
  unsigned int u = __float_as_uint(f);
  u += 0x7FFFu + ((u >> 16) & 1u);
  return (unsigned short)(u >> 16);
}

__device__ __forceinline__ f32x4 mfma16(s16x8 a, s16x8 b, f32x4 c) {
  return __builtin_amdgcn_mfma_f32_16x16x32_bf16(
      __builtin_bit_cast(bf16x8, a), __builtin_bit_cast(bf16x8, b), c, 0, 0, 0);
}

__device__ __forceinline__ void gload16(const unsigned short* g, unsigned short* l) {
  __builtin_amdgcn_global_load_lds(
      (const __attribute__((address_space(1))) unsigned int*)(const void*)g,
      (__attribute__((address_space(3))) unsigned int*)(void*)l, 16, 0, 0);
}

#define BAR()  asm volatile("s_barrier" ::: "memory")
#define LGK0() do { asm volatile("s_waitcnt lgkmcnt(0)" ::: "memory"); \
                    __builtin_amdgcn_sched_barrier(0); } while (0)
#define VM4()  asm volatile("s_waitcnt vmcnt(4)" ::: "memory")
#define VM0()  asm volatile("s_waitcnt vmcnt(0)" ::: "memory")

// --- prep: weight transpose f32->bf16 [N][K], te conv, embed+router --------
// blocks: [0,6144) wtrans | [6144,22144) te conv | [22144,24192) embed+router
__global__ __launch_bounds__(256) void prep_all_kernel(
    const float* __restrict__ Wqkv, const float* __restrict__ Wo,
    const float* __restrict__ W1, const float* __restrict__ W2,
    const float* __restrict__ te,
    unsigned short* __restrict__ WqkvT, unsigned short* __restrict__ WoT,
    unsigned short* __restrict__ W1T, unsigned short* __restrict__ W2T,
    unsigned short* __restrict__ teb,
    const int* __restrict__ ids, const float* __restrict__ pe,
    const float* __restrict__ Wr, const float* __restrict__ br,
    float* __restrict__ res, float* __restrict__ probs,
    float* __restrict__ depth_ws, float* __restrict__ out_depth) {
  const int bid = blockIdx.x;
  const int tid = threadIdx.x;
  __shared__ unsigned short t[64][68];
  __shared__ float red[4][3];
  if (bid >= 22144) {
    // ---- embed + router (1 block per token) ----
    int row = bid - 22144;
    int s = row & (SS - 1);
    int id = ids[row];
    int d = tid * 4;
    float4 a = *(const float4*)(te + (long)id * DD + d);
    float4 p = *(const float4*)(pe + (long)s * DD + d);
    float4 o; o.x = a.x + p.x; o.y = a.y + p.y; o.z = a.z + p.z; o.w = a.w + p.w;
    *(float4*)(res + (long)row * DD + d) = o;
    float a0 = 0.f, a1 = 0.f, a2 = 0.f;
    float hv[4] = {o.x, o.y, o.z, o.w};
#pragma unroll
    for (int j = 0; j < 4; ++j) {
      int dd = d + j;
      a0 += hv[j] * Wr[dd * 3 + 0];
      a1 += hv[j] * Wr[dd * 3 + 1];
      a2 += hv[j] * Wr[dd * 3 + 2];
    }
    for (int off = 32; off; off >>= 1) {
      a0 += __shfl_down(a0, off);
      a1 += __shfl_down(a1, off);
      a2 += __shfl_down(a2, off);
    }
    int wave = tid >> 6;
    if ((tid & 63) == 0) { red[wave][0] = a0; red[wave][1] = a1; red[wave][2] = a2; }
    __syncthreads();
    if (tid == 0) {
      a0 = red[0][0] + red[1][0] + red[2][0] + red[3][0] + br[0];
      a1 = red[0][1] + red[1][1] + red[2][1] + red[3][1] + br[1];
      a2 = red[0][2] + red[1][2] + red[2][2] + red[3][2] + br[2];
      float m = fmaxf(a0, fmaxf(a1, a2));
      float e0 = expf(a0 - m), e1 = expf(a1 - m), e2 = expf(a2 - m);
      float inv = 1.f / (e0 + e1 + e2);
      probs[row * 3 + 0] = e0 * inv;
      probs[row * 3 + 1] = e1 * inv;
      probs[row * 3 + 2] = e2 * inv;
      int am = 0; float bv = a0;
      if (a1 > bv) { bv = a1; am = 1; }
      if (a2 > bv) { bv = a2; am = 2; }
      float dm = (float)(am + 1);
      depth_ws[row] = dm;
      out_depth[row] = dm;
    }
    return;
  }
  if (bid >= 6144) {
    long i = ((long)(bid - 6144) * 256 + tid) * 8;
    float4 v0 = *(const float4*)(te + i);
    float4 v1 = *(const float4*)(te + i + 4);
    ushort4 a, b;
    a.x = f2bf(v0.x); a.y = f2bf(v0.y); a.z = f2bf(v0.z); a.w = f2bf(v0.w);
    b.x = f2bf(v1.x); b.y = f2bf(v1.y); b.z = f2bf(v1.z); b.w = f2bf(v1.w);
    *(ushort4*)(teb + i) = a;
    *(ushort4*)(teb + i + 4) = b;
    return;
  }
  const float* src; unsigned short* dst; int Kd, Nd, local;
  if (bid < 1536) {
    int l = (bid >= 768);
    local = bid - l * 768;
    src = Wqkv + (long)l * DD * 3 * DD; dst = WqkvT + (long)l * 3 * DD * DD;
    Kd = DD; Nd = 3 * DD;
  } else if (bid < 2048) {
    int l = (bid - 1536) >> 8; local = (bid - 1536) & 255;
    src = Wo + (long)l * DD * DD; dst = WoT + (long)l * DD * DD;
    Kd = DD; Nd = DD;
  } else if (bid < 4096) {
    int l = (bid - 2048) >> 10; local = (bid - 2048) & 1023;
    src = W1 + (long)l * DD * DFFN; dst = W1T + (long)l * DFFN * DD;
    Kd = DD; Nd = DFFN;
  } else {
    int l = (bid - 4096) >> 10; local = (bid - 4096) & 1023;
    src = W2 + (long)l * DFFN * DD; dst = W2T + (long)l * DD * DFFN;
    Kd = DFFN; Nd = DD;
  }
  const int tn = Nd >> 6;
  const int n0 = (local % tn) * 64, k0 = (local / tn) * 64;
#pragma unroll
  for (int c = 0; c < 4; ++c) {
    int p = tid + c * 256;
    int kr = p >> 4, nc = (p & 15) * 4;
    float4 v = *(const float4*)(src + (long)(k0 + kr) * Nd + n0 + nc);
    t[nc + 0][kr] = f2bf(v.x);
    t[nc + 1][kr] = f2bf(v.y);
    t[nc + 2][kr] = f2bf(v.z);
    t[nc + 3][kr] = f2bf(v.w);
  }
  __syncthreads();
#pragma unroll
  for (int c = 0; c < 4; ++c) {
    int p = tid + c * 256;
    int nr = p >> 4, kc = (p & 15) * 4;
    ushort4 o;
    o.x = t[nr][kc]; o.y = t[nr][kc + 1]; o.z = t[nr][kc + 2]; o.w = t[nr][kc + 3];
    *(ushort4*)(dst + (long)(n0 + nr) * Kd + k0 + kc) = o;
  }
}

__global__ __launch_bounds__(256) void router_finalize_kernel(
    const float* __restrict__ probs, float* __restrict__ out_loss) {
  __shared__ float red[256][3];
  int t = threadIdx.x;
  float s0 = 0.f, s1 = 0.f, s2 = 0.f;
  for (int r = t; r < NTOK; r += 256) {
    s0 += probs[r * 3 + 0]; s1 += probs[r * 3 + 1]; s2 += probs[r * 3 + 2];
  }
  red[t][0] = s0; red[t][1] = s1; red[t][2] = s2;
  __syncthreads();
  for (int off = 128; off; off >>= 1) {
    if (t < off) {
      red[t][0] += red[t + off][0];
      red[t][1] += red[t + off][1];
      red[t][2] += red[t + off][2];
    }
    __syncthreads();
  }
  if (t == 0) {
    float i0 = red[0][0] / NTOK, i1 = red[0][1] / NTOK, i2 = red[0][2] / NTOK;
    out_loss[0] = (float)RSTEPS * (i0 * i0 + i1 * i1 + i2 * i2);
  }
}

// ---------------- layernorm: f32 in -> bf16 out ----------------------------
__global__ __launch_bounds__(256) void ln_kernel(
    const float* __restrict__ x, const float* __restrict__ g,
    const float* __restrict__ b, unsigned short* __restrict__ y) {
  int row = blockIdx.x;
  int t = threadIdx.x;
  float4 v = *(const float4*)(x + (long)row * DD + t * 4);
  float s = v.x + v.y + v.z + v.w;
  float q = v.x * v.x + v.y * v.y + v.z * v.z + v.w * v.w;
  for (int off = 32; off; off >>= 1) {
    s += __shfl_down(s, off);
    q += __shfl_down(q, off);
  }
  __shared__ float rs[4], rq[4];
  int wave = t >> 6;
  if ((t & 63) == 0) { rs[wave] = s; rq[wave] = q; }
  __syncthreads();
  float S_ = rs[0] + rs[1] + rs[2] + rs[3];
  float Q_ = rq[0] + rq[1] + rq[2] + rq[3];
  float mu = S_ * (1.f / DD);
  float var = Q_ * (1.f / DD) - mu * mu;
  float rstd = rsqrtf(var + 1e-5f);
  int d = t * 4;
  float4 gg = *(const float4*)(g + d);
  float4 bb = *(const float4*)(b + d);
  ushort4 ov;
  ov.x = f2bf((v.x - mu) * rstd * gg.x + bb.x);
  ov.y = f2bf((v.y - mu) * rstd * gg.y + bb.y);
  ov.z = f2bf((v.z - mu) * rstd * gg.z + bb.z);
  ov.w = f2bf((v.w - mu) * rstd * gg.w + bb.w);
  *(ushort4*)(y + (long)row * DD + d) = ov;
}

// ================= 256x256 8-phase GEMM (T2+T3+T4+T5) ======================
__device__ __forceinline__ void stageA8(unsigned short* S, int buf, int qm,
    const unsigned short* A, int lda, long m0, int kt, int tid) {
  unsigned short* dst = S + buf * 32768 + qm * 8192;
#pragma unroll
  for (int c = 0; c < 2; ++c) {
    int idx = tid + c * 512;
    int L = (idx << 4) ^ (((idx >> 5) & 1) << 5);
    int band = L >> 13, row = (L >> 7) & 63, kel = (L & 127) >> 1;
    gload16(A + (m0 + band * 128 + qm * 64 + row) * (long)lda + kt * 64 + kel,
            dst + idx * 8);
  }
}

__device__ __forceinline__ void stageB8(unsigned short* S, int buf, int qn,
    const unsigned short* Bt, int ldb, long n0, int kt, int tid) {
  unsigned short* dst = S + buf * 32768 + 16384 + qn * 8192;
#pragma unroll
  for (int c = 0; c < 2; ++c) {
    int idx = tid + c * 512;
    int L = (idx << 4) ^ (((idx >> 5) & 1) << 5);
    int band = L >> 12, row = (L >> 7) & 31, kel = (L & 127) >> 1;
    gload16(Bt + (n0 + band * 64 + qn * 32 + row) * (long)ldb + kt * 64 + kel,
            dst + idx * 8);
  }
}

__device__ __forceinline__ void read_af8(const unsigned short* S, int base,
    int wm, int l16, int g, s16x8 af[2][4]) {
  const int swz = ((l16 >> 2) & 1) << 5;
#pragma unroll
  for (int kk = 0; kk < 2; ++kk)
#pragma unroll
    for (int mf = 0; mf < 4; ++mf) {
      int L = (wm * 8192 + (mf * 16 + l16) * 128 + (kk * 32 + g * 8) * 2) ^ swz;
      af[kk][mf] = *(const s16x8*)(S + base + (L >> 1));
    }
}

__device__ __forceinline__ void read_bf8(const unsigned short* S, int base,
    int wn, int l16, int g, s16x8 bf[2][2]) {
  const int swz = ((l16 >> 2) & 1) << 5;
#pragma unroll
  for (int kk = 0; kk < 2; ++kk)
#pragma unroll
    for (int nf = 0; nf < 2; ++nf) {
      int L = (wn * 4096 + (nf * 16 + l16) * 128 + (kk * 32 + g * 8) * 2) ^ swz;
      bf[kk][nf] = *(const s16x8*)(S + base + (L >> 1));
    }
}

template<int QM, int QN>
__device__ __forceinline__ void do_mfma8(f32x4 acc[8][4],
    const s16x8 af[2][4], const s16x8 bf[2][2]) {
  __builtin_amdgcn_s_setprio(1);
#pragma unroll
  for (int kk = 0; kk < 2; ++kk)
#pragma unroll
    for (int mf = 0; mf < 4; ++mf)
#pragma unroll
      for (int nf = 0; nf < 2; ++nf)
        acc[QM * 4 + mf][QN * 2 + nf] =
            mfma16(af[kk][mf], bf[kk][nf], acc[QM * 4 + mf][QN * 2 + nf]);
  __builtin_amdgcn_s_setprio(0);
}

template<int CBF16, int BIAS, int GELU_ACT>
__global__ __launch_bounds__(512, 1) void gemm256_kernel(
    const unsigned short* __restrict__ A, int lda,
    const unsigned short* __restrict__ Bt, int ldb,
    void* __restrict__ Cv, int ldc,
    const float* __restrict__ bias, int K, int Mblocks) {
  __shared__ unsigned short S[65536];
  const int tid = threadIdx.x;
  const int lane = tid & 63, wave = tid >> 6;
  const int g = lane >> 4, l16 = lane & 15;
  const int wm = wave >> 2, wn = wave & 3;
  const int nwg = gridDim.x * gridDim.y;
  const int orig = blockIdx.x + blockIdx.y * gridDim.x;
  const int q = nwg >> 3, r = nwg & 7;
  const int xcd = orig & 7, loc = orig >> 3;
  const int wgid = (xcd < r ? xcd * (q + 1) : r * (q + 1) + (xcd - r) * q) + loc;
  const long m0 = (long)(wgid % Mblocks) * 256;
  const long n0 = (long)(wgid / Mblocks) * 256;

  f32x4 acc[8][4] = {};
  s16x8 af[2][4], bf[2][2];
  const int NI = K >> 7;

  stageA8(S, 0, 0, A, lda, m0, 0, tid);
  stageA8(S, 0, 1, A, lda, m0, 0, tid);
  stageB8(S, 0, 0, Bt, ldb, n0, 0, tid);
  stageB8(S, 0, 1, Bt, ldb, n0, 0, tid);
  stageA8(S, 1, 0, A, lda, m0, 1, tid);
  stageB8(S, 1, 1, Bt, ldb, n0, 1, tid);
  VM4(); BAR();

  for (int i = 0; i < NI; ++i) {
    const int kt1 = 2 * i + 1, kt2 = 2 * i + 2, kt3 = 2 * i + 3;
    const bool more = (i + 1 < NI);
    read_af8(S, 0, wm, l16, g, af);
    read_bf8(S, 16384, wn, l16, g, bf);
    stageA8(S, 1, 1, A, lda, m0, kt1, tid);
    BAR(); LGK0();
    do_mfma8<0, 0>(acc, af, bf);
    BAR();
    read_bf8(S, 16384 + 8192, wn, l16, g, bf);
    stageB8(S, 1, 0, Bt, ldb, n0, kt1, tid);
    BAR(); LGK0();
    do_mfma8<0, 1>(acc, af, bf);
    BAR();
    read_af8(S, 8192, wm, l16, g, af);
    if (more) stageA8(S, 0, 0, A, lda, m0, kt2, tid);
    BAR(); LGK0();
    do_mfma8<1, 1>(acc, af, bf);
    BAR();
    read_bf8(S, 16384, wn, l16, g, bf);
    if (more) stageB8(S, 0, 1, Bt, ldb, n0, kt2, tid);
    BAR(); LGK0();
    do_mfma8<1, 0>(acc, af, bf);
    if (more) { VM4(); } else { VM0(); }
    BAR();
    read_af8(S, 32768, wm, l16, g, af);
    read_bf8(S, 32768 + 16384, wn, l16, g, bf);
    if (more) stageA8(S, 0, 1, A, lda, m0, kt2, tid);
    BAR(); LGK0();
    do_mfma8<0, 0>(acc, af, bf);
    BAR();
    read_bf8(S, 32768 + 16384 + 8192, wn, l16, g, bf);
    if (more) stageB8(S, 0, 0, Bt, ldb, n0, kt2, tid);
    BAR(); LGK0();
    do_mfma8<0, 1>(acc, af, bf);
    BAR();
    read_af8(S, 32768 + 8192, wm, l16, g, af);
    if (more) stageA8(S, 1, 0, A, lda, m0, kt3, tid);
    BAR(); LGK0();
    do_mfma8<1, 1>(acc, af, bf);
    BAR();
    read_bf8(S, 32768 + 16384, wn, l16, g, bf);
    if (more) stageB8(S, 1, 1, Bt, ldb, n0, kt3, tid);
    BAR(); LGK0();
    do_mfma8<1, 0>(acc, af, bf);
    VM4(); BAR();
  }

#pragma unroll
  for (int mf = 0; mf < 8; ++mf) {
#pragma unroll
    for (int nf = 0; nf < 4; ++nf) {
      long row0 = m0 + wm * 128 + mf * 16 + g * 4;
      long col = n0 + wn * 64 + nf * 16 + l16;
      float bv = BIAS ? bias[col] : 0.f;
#pragma unroll
      for (int rr = 0; rr < 4; ++rr) {
        float v = acc[mf][nf][rr] + bv;
        if (GELU_ACT) {
          float x3 = v * v * v;
          v = 0.5f * v * (1.f + tanhf(0.7978845608028654f * (v + 0.044715f * x3)));
        }
        if (CBF16) ((unsigned short*)Cv)[(row0 + rr) * (long)ldc + col] = f2bf(v);
        else       ((float*)Cv)[(row0 + rr) * (long)ldc + col] = v;
      }
    }
  }
}

// ---------------- GEMM (m97 structure + XCD-chunked m-fast swizzle) --------
// QKVW: Q/K cols -> Cv, V cols (>=2048) -> vtw transposed [BH][64][S].
template<int BN, int CBF16, int BIAS, int RESID, int GELU_ACT, int QKVW>
__global__ __launch_bounds__(256) void gemm128_kernel(
    const unsigned short* __restrict__ A, int lda,
    const unsigned short* __restrict__ Bt, int ldb,
    void* __restrict__ Cv, int ldc,
    const float* __restrict__ bias,
    const float* __restrict__ resid, int ldr,
    unsigned short* __restrict__ vtw,
    int K) {
  constexpr int BM = 128;
  constexpr int WN = BN / 2;
  constexpr int MR = 4;
  constexpr int NR = WN / 16;
  __shared__ unsigned short As[BM * 64];
  __shared__ unsigned short Bs[BN * 64];
  const int tid = threadIdx.x;
  const int lane = tid & 63, wave = tid >> 6;
  const int g = lane >> 4, l16 = lane & 15;
  const int wr = wave >> 1, wc = wave & 1;
  int lin = blockIdx.x + blockIdx.y * gridDim.x;
  int per = (gridDim.x * gridDim.y) >> 3;
  int v = (lin & 7) * per + (lin >> 3);
  const long m0 = (long)(v % gridDim.y) * BM;
  const long n0 = (long)(v / gridDim.y) * BN;
  f32x4 acc[MR][NR] = {};
  for (int k0 = 0; k0 < K; k0 += 64) {
    __syncthreads();
#pragma unroll
    for (int c = 0; c < BM / 32; ++c) {
      int p = tid + c * 256;
      int r = p >> 3, kq = (p & 7) * 8;
      gload16(A + (m0 + r) * (long)lda + k0 + kq, &As[p * 8]);
    }
#pragma unroll
    for (int c = 0; c < BN / 32; ++c) {
      int p = tid + c * 256;
      int r = p >> 3, kq = (p & 7) * 8;
      gload16(Bt + (n0 + r) * (long)ldb + k0 + kq, &Bs[p * 8]);
    }
    __syncthreads();
#pragma unroll
    for (int kk = 0; kk < 2; ++kk) {
      s16x8 af[MR], bf[NR];
#pragma unroll
      for (int m = 0; m < MR; ++m)
        af[m] = *(const s16x8*)&As[(wr * 64 + m * 16 + l16) * 64 + kk * 32 + g * 8];
#pragma unroll
      for (int n = 0; n < NR; ++n)
        bf[n] = *(const s16x8*)&Bs[(wc * WN + n * 16 + l16) * 64 + kk * 32 + g * 8];
#pragma unroll
      for (int m = 0; m < MR; ++m)
#pragma unroll
        for (int n = 0; n < NR; ++n)
          acc[m][n] = mfma16(af[m], bf[n], acc[m][n]);
    }
  }
  const bool vblk = QKVW && (n0 >= 2048);
#pragma unroll
  for (int m = 0; m < MR; ++m) {
#pragma unroll
    for (int n = 0; n < NR; ++n) {
      long row_base = m0 + wr * 64 + m * 16 + g * 4;
      long col = n0 + wc * WN + n * 16 + l16;
      float bv = BIAS ? bias[col] : 0.f;
      float vv4[4];
#pragma unroll
      for (int r = 0; r < 4; ++r) {
        long row = row_base + r;
        float vv = acc[m][n][r] + bv;
        if (RESID) vv += resid[row * (long)ldr + col];
        if (GELU_ACT) {
          float x3 = vv * vv * vv;
          vv = 0.5f * vv * (1.f + tanhf(0.7978845608028654f * (vv + 0.044715f * x3)));
        }
        vv4[r] = vv;
      }
      if (QKVW && vblk) {
        int rel = (int)col - 2048;
        int h = rel >> 6, d = rel & 63;
        int b = (int)(row_base >> 10);
        int s = (int)(row_base & 1023);
        ushort4 o;
        o.x = f2bf(vv4[0]); o.y = f2bf(vv4[1]);
        o.z = f2bf(vv4[2]); o.w = f2bf(vv4[3]);
        *(ushort4*)(vtw + (((long)(b * 16 + h) * 64 + d) * SS + s)) = o;
      } else {
#pragma unroll
        for (int r = 0; r < 4; ++r) {
          long row = row_base + r;
          if (CBF16) ((unsigned short*)Cv)[row * (long)ldc + col] = f2bf(vv4[r]);
          else       ((float*)Cv)[row * (long)ldc + col] = vv4[r];
        }
      }
    }
  }
}

// ------- 128x64-tile GEMM, 8 waves (2 waves/SIMD at 256-block grids) -------
// wave grid 4m x 2n, each wave 32x32 output (MR=NR=2). SELW = fused select.
template<int CBF16, int BIAS, int RESID, int SELW>
__global__ __launch_bounds__(512) void gemm64w8_kernel(
    const unsigned short* __restrict__ A, int lda,
    const unsigned short* __restrict__ Bt, int ldb,
    void* __restrict__ Cv, int ldc,
    const float* __restrict__ bias,
    const float* __restrict__ resid, int ldr,
    const float* __restrict__ depth_ws, float stepf,
    int K) {
  __shared__ unsigned short As[128 * 64];
  __shared__ unsigned short Bs[64 * 64];
  const int tid = threadIdx.x;
  const int lane = tid & 63, wave = tid >> 6;
  const int g = lane >> 4, l16 = lane & 15;
  const int wr = wave >> 1, wc = wave & 1;
  int lin = blockIdx.x + blockIdx.y * gridDim.x;
  int per = (gridDim.x * gridDim.y) >> 3;
  int v = (lin & 7) * per + (lin >> 3);
  const long m0 = (long)(v % gridDim.y) * 128;
  const long n0 = (long)(v / gridDim.y) * 64;
  f32x4 acc[2][2] = {};
  for (int k0 = 0; k0 < K; k0 += 64) {
    __syncthreads();
#pragma unroll
    for (int c = 0; c < 2; ++c) {
      int p = tid + c * 512;
      int r = p >> 3, kq = (p & 7) * 8;
      gload16(A + (m0 + r) * (long)lda + k0 + kq, &As[p * 8]);
    }
    {
      int r = tid >> 3, kq = (tid & 7) * 8;
      gload16(Bt + (n0 + r) * (long)ldb + k0 + kq, &Bs[tid * 8]);
    }
    __syncthreads();
#pragma unroll
    for (int kk = 0; kk < 2; ++kk) {
      s16x8 af[2], bf[2];
#pragma unroll
      for (int m = 0; m < 2; ++m)
        af[m] = *(const s16x8*)&As[(wr * 32 + m * 16 + l16) * 64 + kk * 32 + g * 8];
#pragma unroll
      for (int n = 0; n < 2; ++n)
        bf[n] = *(const s16x8*)&Bs[(wc * 32 + n * 16 + l16) * 64 + kk * 32 + g * 8];
#pragma unroll
      for (int m = 0; m < 2; ++m)
#pragma unroll
        for (int n = 0; n < 2; ++n)
          acc[m][n] = mfma16(af[m], bf[n], acc[m][n]);
    }
  }
#pragma unroll
  for (int m = 0; m < 2; ++m) {
#pragma unroll
    for (int n = 0; n < 2; ++n) {
      long row_base = m0 + wr * 32 + m * 16 + g * 4;
      long col = n0 + wc * 32 + n * 16 + l16;
      float bv = BIAS ? bias[col] : 0.f;
#pragma unroll
      for (int r = 0; r < 4; ++r) {
        long row = row_base + r;
        float vv = acc[m][n][r] + bv;
        if (RESID) vv += resid[row * (long)ldr + col];
        if (SELW) {
          if (depth_ws[row] >= stepf)
            ((float*)Cv)[row * (long)ldc + col] = vv;
        } else if (CBF16) {
          ((unsigned short*)Cv)[row * (long)ldc + col] = f2bf(vv);
        } else {
          ((float*)Cv)[row * (long)ldc + col] = vv;
        }
      }
    }
  }
}

// ---- flash attention: QBLK=64, 4 waves, dbuf, heavy-tiles-first order -----
__global__ __launch_bounds__(256) void attn_kernel(
    const unsigned short* __restrict__ qkv,   // [NTOK][3072] (Q,K used)
    const unsigned short* __restrict__ vt,    // [BH][64][S]
    unsigned short* __restrict__ o) {         // [NTOK][1024]
  __shared__ unsigned short Ks[2][64 * 64];
  __shared__ unsigned short Vs[2][64 * 64];
  __shared__ unsigned short Pl[4][16][72];
  const int qb = gridDim.x - 1 - blockIdx.x;   // heavy (late-causal) blocks first
  const int bh = blockIdx.y;
  const int b = bh >> 4, h = bh & 15;
  const int tid = threadIdx.x, wave = tid >> 6, lane = tid & 63;
  const int g = lane >> 4, l16 = lane & 15;
  const float NEG_INF = -__builtin_inff();
  const int q0 = qb * 64;
  const int qrw = q0 + wave * 16;
  const long rowbase = (long)b * SS;
  const unsigned short* kbase = qkv + rowbase * 3072 + 1024 + h * 64;
  const unsigned short* vbase = vt + (long)bh * 64 * SS;

  const unsigned short* qptr = qkv + (rowbase + qrw + l16) * 3072 + h * 64;
  s16x8 qf0 = *(const s16x8*)(qptr + g * 8);
  s16x8 qf1 = *(const s16x8*)(qptr + 32 + g * 8);

  f32x4 oacc[4] = {};
  float mrun = NEG_INF, lrun = 0.f;

  const int ntile = q0 / 64 + 1;

#pragma unroll
  for (int c = 0; c < 2; ++c) {
    int idx = tid + c * 256;
    int r = idx >> 3;
    int bo = (idx & 7) * 16;
    int sw = (bo ^ ((r & 7) << 4)) >> 1;
    gload16(kbase + (long)r * 3072 + sw, &Ks[0][idx * 8]);
    gload16(vbase + (long)r * SS + 0 + sw, &Vs[0][idx * 8]);
  }
  asm volatile("s_waitcnt vmcnt(0)" ::: "memory");
  __syncthreads();

  for (int t = 0; t < ntile; ++t) {
    const int cur = t & 1;
    const int kv0 = t * 64;
    const unsigned short* ks_cur = &Ks[cur][0];
    const unsigned short* vs_cur = &Vs[cur][0];
    if (t + 1 < ntile) {
      const int kvn = kv0 + 64;
#pragma unroll
      for (int c = 0; c < 2; ++c) {
        int idx = tid + c * 256;
        int r = idx >> 3;
        int bo = (idx & 7) * 16;
        int sw = (bo ^ ((r & 7) << 4)) >> 1;
        gload16(kbase + (long)(kvn + r) * 3072 + sw, &Ks[cur ^ 1][idx * 8]);
        gload16(vbase + (long)r * SS + kvn + sw, &Vs[cur ^ 1][idx * 8]);
      }
    }
    f32x4 accs[4] = {};
#pragma unroll
    for (int ks = 0; ks < 2; ++ks) {
#pragma unroll
      for (int kvb = 0; kvb < 4; ++kvb) {
        int row = kvb * 16 + l16;
        int bo = ((ks * 64 + g * 16) ^ ((l16 & 7) << 4)) >> 1;
        s16x8 kf = *(const s16x8*)&ks_cur[row * 64 + bo];
        accs[kvb] = mfma16(kf, ks ? qf1 : qf0, accs[kvb]);
      }
    }
    const bool needmask = (kv0 + 63 > qrw);
    const int qabs = qrw + l16;
    float sv[4][4];
    float mloc = NEG_INF;
#pragma unroll
    for (int kvb = 0; kvb < 4; ++kvb) {
#pragma unroll
      for (int r = 0; r < 4; ++r) {
        float vv = accs[kvb][r] * 0.125f;
        if (needmask) {
          int kva = kv0 + kvb * 16 + g * 4 + r;
          if (kva > qabs) vv = NEG_INF;
        }
        sv[kvb][r] = vv;
        mloc = fmaxf(mloc, vv);
      }
    }
    mloc = fmaxf(mloc, __shfl_xor(mloc, 16));
    mloc = fmaxf(mloc, __shfl_xor(mloc, 32));
    float mnew = fmaxf(mrun, mloc);
    float alpha = __expf(mrun - mnew);
    float lsum = 0.f;
#pragma unroll
    for (int kvb = 0; kvb < 4; ++kvb) {
      float p0 = __expf(sv[kvb][0] - mnew);
      float p1 = __expf(sv[kvb][1] - mnew);
      float p2 = __expf(sv[kvb][2] - mnew);
      float p3 = __expf(sv[kvb][3] - mnew);
      lsum += (p0 + p1) + (p2 + p3);
      unsigned int w0 = (unsigned)f2bf(p0) | ((unsigned)f2bf(p1) << 16);
      unsigned int w1 = (unsigned)f2bf(p2) | ((unsigned)f2bf(p3) << 16);
      uint2 pw; pw.x = w0; pw.y = w1;
      *(uint2*)&Pl[wave][l16][kvb * 16 + g * 4] = pw;
    }
    lsum += __shfl_xor(lsum, 16);
    lsum += __shfl_xor(lsum, 32);
    lrun = lrun * alpha + lsum;
    mrun = mnew;
    float mult[4];
#pragma unroll
    for (int r = 0; r < 4; ++r) mult[r] = __shfl(alpha, g * 4 + r);
#pragma unroll
    for (int nd = 0; nd < 4; ++nd)
#pragma unroll
      for (int r = 0; r < 4; ++r) oacc[nd][r] *= mult[r];
#pragma unroll
    for (int kh = 0; kh < 2; ++kh) {
      s16x8 pa = *(const s16x8*)&Pl[wave][l16][kh * 32 + g * 8];
#pragma unroll
      for (int nd = 0; nd < 4; ++nd) {
        int row = nd * 16 + l16;
        int bo = ((kh * 64 + g * 16) ^ ((l16 & 7) << 4)) >> 1;
        s16x8 vf = *(const s16x8*)&vs_cur[row * 64 + bo];
        oacc[nd] = mfma16(pa, vf, oacc[nd]);
      }
    }
    asm volatile("s_waitcnt vmcnt(0)" ::: "memory");
    __syncthreads();
  }
  unsigned short* ob = o + (rowbase + qrw) * 1024 + h * 64;
#pragma unroll
  for (int r = 0; r < 4; ++r) {
    float lr = __shfl(lrun, g * 4 + r);
    float inv = 1.f / lr;
#pragma unroll
    for (int nd = 0; nd < 4; ++nd)
      ob[(long)(g * 4 + r) * 1024 + nd * 16 + l16] = f2bf(oacc[nd][r] * inv);
  }
}

extern "C" void kernel_launch(void* const* d_in, const int* in_sizes, int n_in,
                              void* d_out, int out_size, void* d_ws, size_t ws_size,
                              hipStream_t stream) {
  (void)in_sizes; (void)n_in; (void)out_size; (void)ws_size;
  const int*   ids  = (const int*)d_in[0];
  const float* te   = (const float*)d_in[1];
  const float* pe   = (const float*)d_in[2];
  const float* Wqkv = (const float*)d_in[3];
  const float* bqkv = (const float*)d_in[4];
  const float* Wo   = (const float*)d_in[5];
  const float* bo   = (const float*)d_in[6];
  const float* W1   = (const float*)d_in[7];
  const float* b1   = (const float*)d_in[8];
  const float* W2   = (const float*)d_in[9];
  const float* b2   = (const float*)d_in[10];
  const float* ln1g = (const float*)d_in[11];
  const float* ln1b = (const float*)d_in[12];
  const float* ln2g = (const float*)d_in[13];
  const float* ln2b = (const float*)d_in[14];
  const float* fing = (const float*)d_in[15];
  const float* finb = (const float*)d_in[16];
  const float* Wr   = (const float*)d_in[17];
  const float* br   = (const float*)d_in[18];

  float* logits    = (float*)d_out;
  float* out_depth = logits + (long)NTOK * VV;
  float* out_loss  = out_depth + NTOK;

  char* w = (char*)d_ws;
  float* res            = (float*)w;          w += (long)NTOK * DD * 4;
  float* x              = (float*)w;          w += (long)NTOK * DD * 4;
  unsigned short* hbuf  = (unsigned short*)w; w += (long)NTOK * DD * 2;
  unsigned short* qkvb  = (unsigned short*)w; w += (long)NTOK * 3 * DD * 2;
  unsigned short* obuf  = (unsigned short*)w; w += (long)NTOK * DD * 2;
  unsigned short* ffn1  = (unsigned short*)w; w += (long)NTOK * DFFN * 2;
  unsigned short* vtb   = (unsigned short*)w; w += (long)BB * HH * 64 * SS * 2;
  float* probs          = (float*)w;          w += (long)NTOK * 3 * 4;
  float* depth_ws       = (float*)w;          w += (long)NTOK * 4;
  unsigned short* WqkvT = (unsigned short*)w; w += (long)LLAYERS * 3 * DD * DD * 2;
  unsigned short* WoT   = (unsigned short*)w; w += (long)LLAYERS * DD * DD * 2;
  unsigned short* W1T   = (unsigned short*)w; w += (long)LLAYERS * DFFN * DD * 2;
  unsigned short* W2T   = (unsigned short*)w; w += (long)LLAYERS * DD * DFFN * 2;
  unsigned short* teb   = (unsigned short*)w; w += (long)VV * DD * 2;

  prep_all_kernel<<<6144 + 16000 + NTOK, 256, 0, stream>>>(
      Wqkv, Wo, W1, W2, te, WqkvT, WoT, W1T, W2T, teb,
      ids, pe, Wr, br, res, probs, depth_ws, out_depth);
  router_finalize_kernel<<<1, 256, 0, stream>>>(probs, out_loss);

  for (int step = 0; step < RSTEPS; ++step) {
    for (int l = 0; l < LLAYERS; ++l) {
      const float* xin = (l == 0) ? res : x;
      ln_kernel<<<NTOK, 256, 0, stream>>>(xin, ln1g + l * DD, ln1b + l * DD, hbuf);
      gemm128_kernel<128, 1, 1, 0, 0, 1><<<dim3(3 * DD / 128, NTOK / 128), 256, 0, stream>>>(
          hbuf, DD, WqkvT + (long)l * 3 * DD * DD, DD, qkvb, 3 * DD,
          bqkv + (long)l * 3 * DD, nullptr, 0, vtb, DD);
      attn_kernel<<<dim3(SS / 64, BB * HH), 256, 0, stream>>>(qkvb, vtb, obuf);
      gemm64w8_kernel<0, 1, 1, 0><<<dim3(DD / 64, NTOK / 128), 512, 0, stream>>>(
          obuf, DD, WoT + (long)l * DD * DD, DD, x, DD,
          bo + (long)l * DD, xin, DD, nullptr, 0.f, DD);
      ln_kernel<<<NTOK, 256, 0, stream>>>(x, ln2g + l * DD, ln2b + l * DD, hbuf);
      gemm128_kernel<128, 1, 1, 0, 1, 0><<<dim3(DFFN / 128, NTOK / 128), 256, 0, stream>>>(
          hbuf, DD, W1T + (long)l * DFFN * DD, DD, ffn1, DFFN,
          b1 + (long)l * DFFN, nullptr, 0, nullptr, DD);
      if (l == 0) {
        gemm64w8_kernel<0, 1, 1, 0><<<dim3(DD / 64, NTOK / 128), 512, 0, stream>>>(
            ffn1, DFFN, W2T + (long)l * DD * DFFN, DFFN, x, DD,
            b2 + (long)l * DD, x, DD, nullptr, 0.f, DFFN);
      } else {
        gemm64w8_kernel<0, 1, 1, 1><<<dim3(DD / 64, NTOK / 128), 512, 0, stream>>>(
            ffn1, DFFN, W2T + (long)l * DD * DFFN, DFFN, res, DD,
            b2 + (long)l * DD, x, DD, depth_ws, (float)(step + 1), DFFN);
      }
    }
  }
  ln_kernel<<<NTOK, 256, 0, stream>>>(res, fing, finb, hbuf);
  gemm256_kernel<0, 0, 0><<<dim3(VV / 256, NTOK / 256), 512, 0, stream>>>(
      hbuf, DD, teb, DD, logits, VV, nullptr, DD, NTOK / 256);
}

// Round 11
// 1363.039 us; speedup vs baseline: 1.0738x; 1.0738x over previous
//
#include <hip/hip_runtime.h>
#include <hip/hip_bf16.h>

#define DD 1024
#define SS 1024
#define BB 2
#define HH 16
#define DFFN 4096
#define LLAYERS 2
#define RSTEPS 3
#define VV 32000
#define NTOK (BB*SS)

typedef __attribute__((ext_vector_type(8))) short s16x8;
typedef __attribute__((ext_vector_type(8))) __bf16 bf16x8;
typedef __attribute__((ext_vector_type(4))) float f32x4;

__device__ __forceinline__ unsigned short f2bf(float f) {
  unsigned int u = __float_as_uint(f);
  u += 0x7FFFu + ((u >> 16) & 1u);
  return (unsigned short)(u >> 16);
}

__device__ __forceinline__ f32x4 mfma16(s16x8 a, s16x8 b, f32x4 c) {
  return __builtin_amdgcn_mfma_f32_16x16x32_bf16(
      __builtin_bit_cast(bf16x8, a), __builtin_bit_cast(bf16x8, b), c, 0, 0, 0);
}

__device__ __forceinline__ void gload16(const unsigned short* g, unsigned short* l) {
  __builtin_amdgcn_global_load_lds(
      (const __attribute__((address_space(1))) unsigned int*)(const void*)g,
      (__attribute__((address_space(3))) unsigned int*)(void*)l, 16, 0, 0);
}

#define BAR()  asm volatile("s_barrier" ::: "memory")
#define LGK0() do { asm volatile("s_waitcnt lgkmcnt(0)" ::: "memory"); \
                    __builtin_amdgcn_sched_barrier(0); } while (0)
#define VM8()  asm volatile("s_waitcnt vmcnt(8)" ::: "memory")
#define VM4()  asm volatile("s_waitcnt vmcnt(4)" ::: "memory")
#define VM3()  asm volatile("s_waitcnt vmcnt(3)" ::: "memory")
#define VM0()  asm volatile("s_waitcnt vmcnt(0)" ::: "memory")

// --- prep: weight transpose f32->bf16 [N][K], te conv, embed+router --------
// blocks: [0,6144) wtrans | [6144,22144) te conv | [22144,24192) embed+router
__global__ __launch_bounds__(256) void prep_all_kernel(
    const float* __restrict__ Wqkv, const float* __restrict__ Wo,
    const float* __restrict__ W1, const float* __restrict__ W2,
    const float* __restrict__ te,
    unsigned short* __restrict__ WqkvT, unsigned short* __restrict__ WoT,
    unsigned short* __restrict__ W1T, unsigned short* __restrict__ W2T,
    unsigned short* __restrict__ teb,
    const int* __restrict__ ids, const float* __restrict__ pe,
    const float* __restrict__ Wr, const float* __restrict__ br,
    float* __restrict__ res, float* __restrict__ probs,
    float* __restrict__ depth_ws, float* __restrict__ out_depth) {
  const int bid = blockIdx.x;
  const int tid = threadIdx.x;
  __shared__ unsigned short t[64][68];
  __shared__ float red[4][3];
  if (bid >= 22144) {
    int row = bid - 22144;
    int s = row & (SS - 1);
    int id = ids[row];
    int d = tid * 4;
    float4 a = *(const float4*)(te + (long)id * DD + d);
    float4 p = *(const float4*)(pe + (long)s * DD + d);
    float4 o; o.x = a.x + p.x; o.y = a.y + p.y; o.z = a.z + p.z; o.w = a.w + p.w;
    *(float4*)(res + (long)row * DD + d) = o;
    float a0 = 0.f, a1 = 0.f, a2 = 0.f;
    float hv[4] = {o.x, o.y, o.z, o.w};
#pragma unroll
    for (int j = 0; j < 4; ++j) {
      int dd = d + j;
      a0 += hv[j] * Wr[dd * 3 + 0];
      a1 += hv[j] * Wr[dd * 3 + 1];
      a2 += hv[j] * Wr[dd * 3 + 2];
    }
    for (int off = 32; off; off >>= 1) {
      a0 += __shfl_down(a0, off);
      a1 += __shfl_down(a1, off);
      a2 += __shfl_down(a2, off);
    }
    int wave = tid >> 6;
    if ((tid & 63) == 0) { red[wave][0] = a0; red[wave][1] = a1; red[wave][2] = a2; }
    __syncthreads();
    if (tid == 0) {
      a0 = red[0][0] + red[1][0] + red[2][0] + red[3][0] + br[0];
      a1 = red[0][1] + red[1][1] + red[2][1] + red[3][1] + br[1];
      a2 = red[0][2] + red[1][2] + red[2][2] + red[3][2] + br[2];
      float m = fmaxf(a0, fmaxf(a1, a2));
      float e0 = expf(a0 - m), e1 = expf(a1 - m), e2 = expf(a2 - m);
      float inv = 1.f / (e0 + e1 + e2);
      probs[row * 3 + 0] = e0 * inv;
      probs[row * 3 + 1] = e1 * inv;
      probs[row * 3 + 2] = e2 * inv;
      int am = 0; float bv = a0;
      if (a1 > bv) { bv = a1; am = 1; }
      if (a2 > bv) { bv = a2; am = 2; }
      float dm = (float)(am + 1);
      depth_ws[row] = dm;
      out_depth[row] = dm;
    }
    return;
  }
  if (bid >= 6144) {
    long i = ((long)(bid - 6144) * 256 + tid) * 8;
    float4 v0 = *(const float4*)(te + i);
    float4 v1 = *(const float4*)(te + i + 4);
    ushort4 a, b;
    a.x = f2bf(v0.x); a.y = f2bf(v0.y); a.z = f2bf(v0.z); a.w = f2bf(v0.w);
    b.x = f2bf(v1.x); b.y = f2bf(v1.y); b.z = f2bf(v1.z); b.w = f2bf(v1.w);
    *(ushort4*)(teb + i) = a;
    *(ushort4*)(teb + i + 4) = b;
    return;
  }
  const float* src; unsigned short* dst; int Kd, Nd, local;
  if (bid < 1536) {
    int l = (bid >= 768);
    local = bid - l * 768;
    src = Wqkv + (long)l * DD * 3 * DD; dst = WqkvT + (long)l * 3 * DD * DD;
    Kd = DD; Nd = 3 * DD;
  } else if (bid < 2048) {
    int l = (bid - 1536) >> 8; local = (bid - 1536) & 255;
    src = Wo + (long)l * DD * DD; dst = WoT + (long)l * DD * DD;
    Kd = DD; Nd = DD;
  } else if (bid < 4096) {
    int l = (bid - 2048) >> 10; local = (bid - 2048) & 1023;
    src = W1 + (long)l * DD * DFFN; dst = W1T + (long)l * DFFN * DD;
    Kd = DD; Nd = DFFN;
  } else {
    int l = (bid - 4096) >> 10; local = (bid - 4096) & 1023;
    src = W2 + (long)l * DFFN * DD; dst = W2T + (long)l * DD * DFFN;
    Kd = DFFN; Nd = DD;
  }
  const int tn = Nd >> 6;
  const int n0 = (local % tn) * 64, k0 = (local / tn) * 64;
#pragma unroll
  for (int c = 0; c < 4; ++c) {
    int p = tid + c * 256;
    int kr = p >> 4, nc = (p & 15) * 4;
    float4 v = *(const float4*)(src + (long)(k0 + kr) * Nd + n0 + nc);
    t[nc + 0][kr] = f2bf(v.x);
    t[nc + 1][kr] = f2bf(v.y);
    t[nc + 2][kr] = f2bf(v.z);
    t[nc + 3][kr] = f2bf(v.w);
  }
  __syncthreads();
#pragma unroll
  for (int c = 0; c < 4; ++c) {
    int p = tid + c * 256;
    int nr = p >> 4, kc = (p & 15) * 4;
    ushort4 o;
    o.x = t[nr][kc]; o.y = t[nr][kc + 1]; o.z = t[nr][kc + 2]; o.w = t[nr][kc + 3];
    *(ushort4*)(dst + (long)(n0 + nr) * Kd + k0 + kc) = o;
  }
}

__global__ __launch_bounds__(256) void router_finalize_kernel(
    const float* __restrict__ probs, float* __restrict__ out_loss) {
  __shared__ float red[256][3];
  int t = threadIdx.x;
  float s0 = 0.f, s1 = 0.f, s2 = 0.f;
  for (int r = t; r < NTOK; r += 256) {
    s0 += probs[r * 3 + 0]; s1 += probs[r * 3 + 1]; s2 += probs[r * 3 + 2];
  }
  red[t][0] = s0; red[t][1] = s1; red[t][2] = s2;
  __syncthreads();
  for (int off = 128; off; off >>= 1) {
    if (t < off) {
      red[t][0] += red[t + off][0];
      red[t][1] += red[t + off][1];
      red[t][2] += red[t + off][2];
    }
    __syncthreads();
  }
  if (t == 0) {
    float i0 = red[0][0] / NTOK, i1 = red[0][1] / NTOK, i2 = red[0][2] / NTOK;
    out_loss[0] = (float)RSTEPS * (i0 * i0 + i1 * i1 + i2 * i2);
  }
}

// ---------------- layernorm: f32 in -> bf16 out ----------------------------
__global__ __launch_bounds__(256) void ln_kernel(
    const float* __restrict__ x, const float* __restrict__ g,
    const float* __restrict__ b, unsigned short* __restrict__ y) {
  int row = blockIdx.x;
  int t = threadIdx.x;
  float4 v = *(const float4*)(x + (long)row * DD + t * 4);
  float s = v.x + v.y + v.z + v.w;
  float q = v.x * v.x + v.y * v.y + v.z * v.z + v.w * v.w;
  for (int off = 32; off; off >>= 1) {
    s += __shfl_down(s, off);
    q += __shfl_down(q, off);
  }
  __shared__ float rs[4], rq[4];
  int wave = t >> 6;
  if ((t & 63) == 0) { rs[wave] = s; rq[wave] = q; }
  __syncthreads();
  float S_ = rs[0] + rs[1] + rs[2] + rs[3];
  float Q_ = rq[0] + rq[1] + rq[2] + rq[3];
  float mu = S_ * (1.f / DD);
  float var = Q_ * (1.f / DD) - mu * mu;
  float rstd = rsqrtf(var + 1e-5f);
  int d = t * 4;
  float4 gg = *(const float4*)(g + d);
  float4 bb = *(const float4*)(b + d);
  ushort4 ov;
  ov.x = f2bf((v.x - mu) * rstd * gg.x + bb.x);
  ov.y = f2bf((v.y - mu) * rstd * gg.y + bb.y);
  ov.z = f2bf((v.z - mu) * rstd * gg.z + bb.z);
  ov.w = f2bf((v.w - mu) * rstd * gg.w + bb.w);
  *(ushort4*)(y + (long)row * DD + d) = ov;
}

// ================= 256x256 8-phase GEMM (T2+T3+T4+T5) ======================
__device__ __forceinline__ void stageA8(unsigned short* S, int buf, int qm,
    const unsigned short* A, int lda, long m0, int kt, int tid) {
  unsigned short* dst = S + buf * 32768 + qm * 8192;
#pragma unroll
  for (int c = 0; c < 2; ++c) {
    int idx = tid + c * 512;
    int L = (idx << 4) ^ (((idx >> 5) & 1) << 5);
    int band = L >> 13, row = (L >> 7) & 63, kel = (L & 127) >> 1;
    gload16(A + (m0 + band * 128 + qm * 64 + row) * (long)lda + kt * 64 + kel,
            dst + idx * 8);
  }
}

__device__ __forceinline__ void stageB8(unsigned short* S, int buf, int qn,
    const unsigned short* Bt, int ldb, long n0, int kt, int tid) {
  unsigned short* dst = S + buf * 32768 + 16384 + qn * 8192;
#pragma unroll
  for (int c = 0; c < 2; ++c) {
    int idx = tid + c * 512;
    int L = (idx << 4) ^ (((idx >> 5) & 1) << 5);
    int band = L >> 12, row = (L >> 7) & 31, kel = (L & 127) >> 1;
    gload16(Bt + (n0 + band * 64 + qn * 32 + row) * (long)ldb + kt * 64 + kel,
            dst + idx * 8);
  }
}

__device__ __forceinline__ void read_af8(const unsigned short* S, int base,
    int wm, int l16, int g, s16x8 af[2][4]) {
  const int swz = ((l16 >> 2) & 1) << 5;
#pragma unroll
  for (int kk = 0; kk < 2; ++kk)
#pragma unroll
    for (int mf = 0; mf < 4; ++mf) {
      int L = (wm * 8192 + (mf * 16 + l16) * 128 + (kk * 32 + g * 8) * 2) ^ swz;
      af[kk][mf] = *(const s16x8*)(S + base + (L >> 1));
    }
}

__device__ __forceinline__ void read_bf8(const unsigned short* S, int base,
    int wn, int l16, int g, s16x8 bf[2][2]) {
  const int swz = ((l16 >> 2) & 1) << 5;
#pragma unroll
  for (int kk = 0; kk < 2; ++kk)
#pragma unroll
    for (int nf = 0; nf < 2; ++nf) {
      int L = (wn * 4096 + (nf * 16 + l16) * 128 + (kk * 32 + g * 8) * 2) ^ swz;
      bf[kk][nf] = *(const s16x8*)(S + base + (L >> 1));
    }
}

template<int QM, int QN>
__device__ __forceinline__ void do_mfma8(f32x4 acc[8][4],
    const s16x8 af[2][4], const s16x8 bf[2][2]) {
  __builtin_amdgcn_s_setprio(1);
#pragma unroll
  for (int kk = 0; kk < 2; ++kk)
#pragma unroll
    for (int mf = 0; mf < 4; ++mf)
#pragma unroll
      for (int nf = 0; nf < 2; ++nf)
        acc[QM * 4 + mf][QN * 2 + nf] =
            mfma16(af[kk][mf], bf[kk][nf], acc[QM * 4 + mf][QN * 2 + nf]);
  __builtin_amdgcn_s_setprio(0);
}

template<int CBF16, int BIAS, int GELU_ACT>
__global__ __launch_bounds__(512, 1) void gemm256_kernel(
    const unsigned short* __restrict__ A, int lda,
    const unsigned short* __restrict__ Bt, int ldb,
    void* __restrict__ Cv, int ldc,
    const float* __restrict__ bias, int K, int Mblocks) {
  __shared__ unsigned short S[65536];
  const int tid = threadIdx.x;
  const int lane = tid & 63, wave = tid >> 6;
  const int g = lane >> 4, l16 = lane & 15;
  const int wm = wave >> 2, wn = wave & 3;
  const int nwg = gridDim.x * gridDim.y;
  const int orig = blockIdx.x + blockIdx.y * gridDim.x;
  const int q = nwg >> 3, r = nwg & 7;
  const int xcd = orig & 7, loc = orig >> 3;
  const int wgid = (xcd < r ? xcd * (q + 1) : r * (q + 1) + (xcd - r) * q) + loc;
  const long m0 = (long)(wgid % Mblocks) * 256;
  const long n0 = (long)(wgid / Mblocks) * 256;

  f32x4 acc[8][4] = {};
  s16x8 af[2][4], bf[2][2];
  const int NI = K >> 7;

  stageA8(S, 0, 0, A, lda, m0, 0, tid);
  stageA8(S, 0, 1, A, lda, m0, 0, tid);
  stageB8(S, 0, 0, Bt, ldb, n0, 0, tid);
  stageB8(S, 0, 1, Bt, ldb, n0, 0, tid);
  stageA8(S, 1, 0, A, lda, m0, 1, tid);
  stageB8(S, 1, 1, Bt, ldb, n0, 1, tid);
  VM4(); BAR();

  for (int i = 0; i < NI; ++i) {
    const int kt1 = 2 * i + 1, kt2 = 2 * i + 2, kt3 = 2 * i + 3;
    const bool more = (i + 1 < NI);
    read_af8(S, 0, wm, l16, g, af);
    read_bf8(S, 16384, wn, l16, g, bf);
    stageA8(S, 1, 1, A, lda, m0, kt1, tid);
    BAR(); LGK0();
    do_mfma8<0, 0>(acc, af, bf);
    BAR();
    read_bf8(S, 16384 + 8192, wn, l16, g, bf);
    stageB8(S, 1, 0, Bt, ldb, n0, kt1, tid);
    BAR(); LGK0();
    do_mfma8<0, 1>(acc, af, bf);
    BAR();
    read_af8(S, 8192, wm, l16, g, af);
    if (more) stageA8(S, 0, 0, A, lda, m0, kt2, tid);
    BAR(); LGK0();
    do_mfma8<1, 1>(acc, af, bf);
    BAR();
    read_bf8(S, 16384, wn, l16, g, bf);
    if (more) stageB8(S, 0, 1, Bt, ldb, n0, kt2, tid);
    BAR(); LGK0();
    do_mfma8<1, 0>(acc, af, bf);
    if (more) { VM4(); } else { VM0(); }
    BAR();
    read_af8(S, 32768, wm, l16, g, af);
    read_bf8(S, 32768 + 16384, wn, l16, g, bf);
    if (more) stageA8(S, 0, 1, A, lda, m0, kt2, tid);
    BAR(); LGK0();
    do_mfma8<0, 0>(acc, af, bf);
    BAR();
    read_bf8(S, 32768 + 16384 + 8192, wn, l16, g, bf);
    if (more) stageB8(S, 0, 0, Bt, ldb, n0, kt2, tid);
    BAR(); LGK0();
    do_mfma8<0, 1>(acc, af, bf);
    BAR();
    read_af8(S, 32768 + 8192, wm, l16, g, af);
    if (more) stageA8(S, 1, 0, A, lda, m0, kt3, tid);
    BAR(); LGK0();
    do_mfma8<1, 1>(acc, af, bf);
    BAR();
    read_bf8(S, 32768 + 16384, wn, l16, g, bf);
    if (more) stageB8(S, 1, 1, Bt, ldb, n0, kt3, tid);
    BAR(); LGK0();
    do_mfma8<1, 0>(acc, af, bf);
    VM4(); BAR();
  }

#pragma unroll
  for (int mf = 0; mf < 8; ++mf) {
#pragma unroll
    for (int nf = 0; nf < 4; ++nf) {
      long row0 = m0 + wm * 128 + mf * 16 + g * 4;
      long col = n0 + wn * 64 + nf * 16 + l16;
      float bv = BIAS ? bias[col] : 0.f;
#pragma unroll
      for (int rr = 0; rr < 4; ++rr) {
        float v = acc[mf][nf][rr] + bv;
        if (GELU_ACT) {
          float x3 = v * v * v;
          v = 0.5f * v * (1.f + tanhf(0.7978845608028654f * (v + 0.044715f * x3)));
        }
        if (CBF16) ((unsigned short*)Cv)[(row0 + rr) * (long)ldc + col] = f2bf(v);
        else       ((float*)Cv)[(row0 + rr) * (long)ldc + col] = v;
      }
    }
  }
}

// -------- 128xBN GEMM, double-buffered counted-vmcnt 2-phase (T3-lite) -----
// QKVW: Q/K cols -> Cv, V cols (>=2048) -> vtw transposed [BH][64][S].
template<int BN, int CBF16, int BIAS, int RESID, int GELU_ACT, int QKVW>
__global__ __launch_bounds__(256) void gemm128_kernel(
    const unsigned short* __restrict__ A, int lda,
    const unsigned short* __restrict__ Bt, int ldb,
    void* __restrict__ Cv, int ldc,
    const float* __restrict__ bias,
    const float* __restrict__ resid, int ldr,
    unsigned short* __restrict__ vtw,
    int K) {
  constexpr int BM = 128;
  constexpr int WN = BN / 2;
  constexpr int MR = 4;
  constexpr int NR = WN / 16;
  static_assert(BM / 32 + BN / 32 == 8, "vmcnt(8) literal assumes 8 loads/thread");
  __shared__ unsigned short As[2][BM * 64];
  __shared__ unsigned short Bs[2][BN * 64];
  const int tid = threadIdx.x;
  const int lane = tid & 63, wave = tid >> 6;
  const int g = lane >> 4, l16 = lane & 15;
  const int wr = wave >> 1, wc = wave & 1;
  int lin = blockIdx.x + blockIdx.y * gridDim.x;
  int per = (gridDim.x * gridDim.y) >> 3;
  int v = (lin & 7) * per + (lin >> 3);
  const long m0 = (long)(v % gridDim.y) * BM;
  const long n0 = (long)(v / gridDim.y) * BN;
  f32x4 acc[MR][NR] = {};
  const int NT = K >> 6;

  auto stage = [&](int buf, int kt) {
    const int k0 = kt * 64;
#pragma unroll
    for (int c = 0; c < BM / 32; ++c) {
      int p = tid + c * 256;
      int r = p >> 3, kq = (p & 7) * 8;
      gload16(A + (m0 + r) * (long)lda + k0 + kq, &As[buf][p * 8]);
    }
#pragma unroll
    for (int c = 0; c < BN / 32; ++c) {
      int p = tid + c * 256;
      int r = p >> 3, kq = (p & 7) * 8;
      gload16(Bt + (n0 + r) * (long)ldb + k0 + kq, &Bs[buf][p * 8]);
    }
  };

  stage(0, 0);
  for (int kt = 0; kt < NT; ++kt) {
    const int cur = kt & 1;
    const bool more = (kt + 1 < NT);
    if (more) { stage(cur ^ 1, kt + 1); VM8(); } else { VM0(); }
    BAR();
#pragma unroll
    for (int kk = 0; kk < 2; ++kk) {
      s16x8 af[MR], bf[NR];
#pragma unroll
      for (int m = 0; m < MR; ++m)
        af[m] = *(const s16x8*)&As[cur][(wr * 64 + m * 16 + l16) * 64 + kk * 32 + g * 8];
#pragma unroll
      for (int n = 0; n < NR; ++n)
        bf[n] = *(const s16x8*)&Bs[cur][(wc * WN + n * 16 + l16) * 64 + kk * 32 + g * 8];
#pragma unroll
      for (int m = 0; m < MR; ++m)
#pragma unroll
        for (int n = 0; n < NR; ++n)
          acc[m][n] = mfma16(af[m], bf[n], acc[m][n]);
    }
    BAR();
  }
  const bool vblk = QKVW && (n0 >= 2048);
#pragma unroll
  for (int m = 0; m < MR; ++m) {
#pragma unroll
    for (int n = 0; n < NR; ++n) {
      long row_base = m0 + wr * 64 + m * 16 + g * 4;
      long col = n0 + wc * WN + n * 16 + l16;
      float bv = BIAS ? bias[col] : 0.f;
      float vv4[4];
#pragma unroll
      for (int r = 0; r < 4; ++r) {
        long row = row_base + r;
        float vv = acc[m][n][r] + bv;
        if (RESID) vv += resid[row * (long)ldr + col];
        if (GELU_ACT) {
          float x3 = vv * vv * vv;
          vv = 0.5f * vv * (1.f + tanhf(0.7978845608028654f * (vv + 0.044715f * x3)));
        }
        vv4[r] = vv;
      }
      if (QKVW && vblk) {
        int rel = (int)col - 2048;
        int h = rel >> 6, d = rel & 63;
        int b = (int)(row_base >> 10);
        int s = (int)(row_base & 1023);
        ushort4 o;
        o.x = f2bf(vv4[0]); o.y = f2bf(vv4[1]);
        o.z = f2bf(vv4[2]); o.w = f2bf(vv4[3]);
        *(ushort4*)(vtw + (((long)(b * 16 + h) * 64 + d) * SS + s)) = o;
      } else {
#pragma unroll
        for (int r = 0; r < 4; ++r) {
          long row = row_base + r;
          if (CBF16) ((unsigned short*)Cv)[row * (long)ldc + col] = f2bf(vv4[r]);
          else       ((float*)Cv)[row * (long)ldc + col] = vv4[r];
        }
      }
    }
  }
}

// -- 128x64 GEMM, 8 waves, double-buffered counted-vmcnt; SELW fused select -
template<int CBF16, int BIAS, int RESID, int SELW>
__global__ __launch_bounds__(512) void gemm64w8_kernel(
    const unsigned short* __restrict__ A, int lda,
    const unsigned short* __restrict__ Bt, int ldb,
    void* __restrict__ Cv, int ldc,
    const float* __restrict__ bias,
    const float* __restrict__ resid, int ldr,
    const float* __restrict__ depth_ws, float stepf,
    int K) {
  __shared__ unsigned short As[2][128 * 64];
  __shared__ unsigned short Bs[2][64 * 64];
  const int tid = threadIdx.x;
  const int lane = tid & 63, wave = tid >> 6;
  const int g = lane >> 4, l16 = lane & 15;
  const int wr = wave >> 1, wc = wave & 1;
  int lin = blockIdx.x + blockIdx.y * gridDim.x;
  int per = (gridDim.x * gridDim.y) >> 3;
  int v = (lin & 7) * per + (lin >> 3);
  const long m0 = (long)(v % gridDim.y) * 128;
  const long n0 = (long)(v / gridDim.y) * 64;
  f32x4 acc[2][2] = {};
  const int NT = K >> 6;

  auto stage = [&](int buf, int kt) {
    const int k0 = kt * 64;
#pragma unroll
    for (int c = 0; c < 2; ++c) {
      int p = tid + c * 512;
      int r = p >> 3, kq = (p & 7) * 8;
      gload16(A + (m0 + r) * (long)lda + k0 + kq, &As[buf][p * 8]);
    }
    {
      int r = tid >> 3, kq = (tid & 7) * 8;
      gload16(Bt + (n0 + r) * (long)ldb + k0 + kq, &Bs[buf][tid * 8]);
    }
  };

  stage(0, 0);
  for (int kt = 0; kt < NT; ++kt) {
    const int cur = kt & 1;
    const bool more = (kt + 1 < NT);
    if (more) { stage(cur ^ 1, kt + 1); VM3(); } else { VM0(); }
    BAR();
#pragma unroll
    for (int kk = 0; kk < 2; ++kk) {
      s16x8 af[2], bf[2];
#pragma unroll
      for (int m = 0; m < 2; ++m)
        af[m] = *(const s16x8*)&As[cur][(wr * 32 + m * 16 + l16) * 64 + kk * 32 + g * 8];
#pragma unroll
      for (int n = 0; n < 2; ++n)
        bf[n] = *(const s16x8*)&Bs[cur][(wc * 32 + n * 16 + l16) * 64 + kk * 32 + g * 8];
#pragma unroll
      for (int m = 0; m < 2; ++m)
#pragma unroll
        for (int n = 0; n < 2; ++n)
          acc[m][n] = mfma16(af[m], bf[n], acc[m][n]);
    }
    BAR();
  }
#pragma unroll
  for (int m = 0; m < 2; ++m) {
#pragma unroll
    for (int n = 0; n < 2; ++n) {
      long row_base = m0 + wr * 32 + m * 16 + g * 4;
      long col = n0 + wc * 32 + n * 16 + l16;
      float bv = BIAS ? bias[col] : 0.f;
#pragma unroll
      for (int r = 0; r < 4; ++r) {
        long row = row_base + r;
        float vv = acc[m][n][r] + bv;
        if (RESID) vv += resid[row * (long)ldr + col];
        if (SELW) {
          if (depth_ws[row] >= stepf)
            ((float*)Cv)[row * (long)ldc + col] = vv;
        } else if (CBF16) {
          ((unsigned short*)Cv)[row * (long)ldc + col] = f2bf(vv);
        } else {
          ((float*)Cv)[row * (long)ldc + col] = vv;
        }
      }
    }
  }
}

// -- flash attention: QBLK=128, 8 waves, swapped QK^T, dbuf, heavy-first ----
__global__ __launch_bounds__(512) void attn_kernel(
    const unsigned short* __restrict__ qkv,   // [NTOK][3072] (Q,K used)
    const unsigned short* __restrict__ vt,    // [BH][64][S]
    unsigned short* __restrict__ o) {         // [NTOK][1024]
  __shared__ unsigned short Ks[2][64 * 64];
  __shared__ unsigned short Vs[2][64 * 64];
  __shared__ unsigned short Pl[8][16][72];
  const int qb = gridDim.x - 1 - blockIdx.x;   // heavy (late-causal) blocks first
  const int bh = blockIdx.y;
  const int b = bh >> 4, h = bh & 15;
  const int tid = threadIdx.x, wave = tid >> 6, lane = tid & 63;
  const int g = lane >> 4, l16 = lane & 15;
  const float NEG_INF = -__builtin_inff();
  const int q0 = qb * 128;
  const int qrw = q0 + wave * 16;
  const long rowbase = (long)b * SS;
  const unsigned short* kbase = qkv + rowbase * 3072 + 1024 + h * 64;
  const unsigned short* vbase = vt + (long)bh * 64 * SS;

  const unsigned short* qptr = qkv + (rowbase + qrw + l16) * 3072 + h * 64;
  s16x8 qf0 = *(const s16x8*)(qptr + g * 8);
  s16x8 qf1 = *(const s16x8*)(qptr + 32 + g * 8);

  f32x4 oacc[4] = {};
  float mrun = NEG_INF, lrun = 0.f;

  const int ntile = q0 / 64 + 2;

  {
    int r = tid >> 3;
    int bo = (tid & 7) * 16;
    int sw = (bo ^ ((r & 7) << 4)) >> 1;
    gload16(kbase + (long)r * 3072 + sw, &Ks[0][tid * 8]);
    gload16(vbase + (long)r * SS + 0 + sw, &Vs[0][tid * 8]);
  }
  asm volatile("s_waitcnt vmcnt(0)" ::: "memory");
  __syncthreads();

  for (int t = 0; t < ntile; ++t) {
    const int cur = t & 1;
    const int kv0 = t * 64;
    const unsigned short* ks_cur = &Ks[cur][0];
    const unsigned short* vs_cur = &Vs[cur][0];
    if (t + 1 < ntile) {
      const int kvn = kv0 + 64;
      int r = tid >> 3;
      int bo = (tid & 7) * 16;
      int sw = (bo ^ ((r & 7) << 4)) >> 1;
      gload16(kbase + (long)(kvn + r) * 3072 + sw, &Ks[cur ^ 1][tid * 8]);
      gload16(vbase + (long)r * SS + kvn + sw, &Vs[cur ^ 1][tid * 8]);
    }
    f32x4 accs[4] = {};
#pragma unroll
    for (int ks = 0; ks < 2; ++ks) {
#pragma unroll
      for (int kvb = 0; kvb < 4; ++kvb) {
        int row = kvb * 16 + l16;
        int bo = ((ks * 64 + g * 16) ^ ((l16 & 7) << 4)) >> 1;
        s16x8 kf = *(const s16x8*)&ks_cur[row * 64 + bo];
        accs[kvb] = mfma16(kf, ks ? qf1 : qf0, accs[kvb]);
      }
    }
    const bool needmask = (kv0 + 63 > qrw);
    const int qabs = qrw + l16;
    float sv[4][4];
    float mloc = NEG_INF;
#pragma unroll
    for (int kvb = 0; kvb < 4; ++kvb) {
#pragma unroll
      for (int r = 0; r < 4; ++r) {
        float vv = accs[kvb][r] * 0.125f;
        if (needmask) {
          int kva = kv0 + kvb * 16 + g * 4 + r;
          if (kva > qabs) vv = NEG_INF;
        }
        sv[kvb][r] = vv;
        mloc = fmaxf(mloc, vv);
      }
    }
    mloc = fmaxf(mloc, __shfl_xor(mloc, 16));
    mloc = fmaxf(mloc, __shfl_xor(mloc, 32));
    float mnew = fmaxf(mrun, mloc);
    float alpha = __expf(mrun - mnew);
    float lsum = 0.f;
#pragma unroll
    for (int kvb = 0; kvb < 4; ++kvb) {
      float p0 = __expf(sv[kvb][0] - mnew);
      float p1 = __expf(sv[kvb][1] - mnew);
      float p2 = __expf(sv[kvb][2] - mnew);
      float p3 = __expf(sv[kvb][3] - mnew);
      lsum += (p0 + p1) + (p2 + p3);
      unsigned int w0 = (unsigned)f2bf(p0) | ((unsigned)f2bf(p1) << 16);
      unsigned int w1 = (unsigned)f2bf(p2) | ((unsigned)f2bf(p3) << 16);
      uint2 pw; pw.x = w0; pw.y = w1;
      *(uint2*)&Pl[wave][l16][kvb * 16 + g * 4] = pw;
    }
    lsum += __shfl_xor(lsum, 16);
    lsum += __shfl_xor(lsum, 32);
    lrun = lrun * alpha + lsum;
    mrun = mnew;
    float mult[4];
#pragma unroll
    for (int r = 0; r < 4; ++r) mult[r] = __shfl(alpha, g * 4 + r);
#pragma unroll
    for (int nd = 0; nd < 4; ++nd)
#pragma unroll
      for (int r = 0; r < 4; ++r) oacc[nd][r] *= mult[r];
#pragma unroll
    for (int kh = 0; kh < 2; ++kh) {
      s16x8 pa = *(const s16x8*)&Pl[wave][l16][kh * 32 + g * 8];
#pragma unroll
      for (int nd = 0; nd < 4; ++nd) {
        int row = nd * 16 + l16;
        int bo = ((kh * 64 + g * 16) ^ ((l16 & 7) << 4)) >> 1;
        s16x8 vf = *(const s16x8*)&vs_cur[row * 64 + bo];
        oacc[nd] = mfma16(pa, vf, oacc[nd]);
      }
    }
    asm volatile("s_waitcnt vmcnt(0)" ::: "memory");
    __syncthreads();
  }
  unsigned short* ob = o + (rowbase + qrw) * 1024 + h * 64;
#pragma unroll
  for (int r = 0; r < 4; ++r) {
    float lr = __shfl(lrun, g * 4 + r);
    float inv = 1.f / lr;
#pragma unroll
    for (int nd = 0; nd < 4; ++nd)
      ob[(long)(g * 4 + r) * 1024 + nd * 16 + l16] = f2bf(oacc[nd][r] * inv);
  }
}

extern "C" void kernel_launch(void* const* d_in, const int* in_sizes, int n_in,
                              void* d_out, int out_size, void* d_ws, size_t ws_size,
                              hipStream_t stream) {
  (void)in_sizes; (void)n_in; (void)out_size; (void)ws_size;
  const int*   ids  = (const int*)d_in[0];
  const float* te   = (const float*)d_in[1];
  const float* pe   = (const float*)d_in[2];
  const float* Wqkv = (const float*)d_in[3];
  const float* bqkv = (const float*)d_in[4];
  const float* Wo   = (const float*)d_in[5];
  const float* bo   = (const float*)d_in[6];
  const float* W1   = (const float*)d_in[7];
  const float* b1   = (const float*)d_in[8];
  const float* W2   = (const float*)d_in[9];
  const float* b2   = (const float*)d_in[10];
  const float* ln1g = (const float*)d_in[11];
  const float* ln1b = (const float*)d_in[12];
  const float* ln2g = (const float*)d_in[13];
  const float* ln2b = (const float*)d_in[14];
  const float* fing = (const float*)d_in[15];
  const float* finb = (const float*)d_in[16];
  const float* Wr   = (const float*)d_in[17];
  const float* br   = (const float*)d_in[18];

  float* logits    = (float*)d_out;
  float* out_depth = logits + (long)NTOK * VV;
  float* out_loss  = out_depth + NTOK;

  char* w = (char*)d_ws;
  float* res            = (float*)w;          w += (long)NTOK * DD * 4;
  float* x              = (float*)w;          w += (long)NTOK * DD * 4;
  unsigned short* hbuf  = (unsigned short*)w; w += (long)NTOK * DD * 2;
  unsigned short* qkvb  = (unsigned short*)w; w += (long)NTOK * 3 * DD * 2;
  unsigned short* obuf  = (unsigned short*)w; w += (long)NTOK * DD * 2;
  unsigned short* ffn1  = (unsigned short*)w; w += (long)NTOK * DFFN * 2;
  unsigned short* vtb   = (unsigned short*)w; w += (long)BB * HH * 64 * SS * 2;
  float* probs          = (float*)w;          w += (long)NTOK * 3 * 4;
  float* depth_ws       = (float*)w;          w += (long)NTOK * 4;
  unsigned short* WqkvT = (unsigned short*)w; w += (long)LLAYERS * 3 * DD * DD * 2;
  unsigned short* WoT   = (unsigned short*)w; w += (long)LLAYERS * DD * DD * 2;
  unsigned short* W1T   = (unsigned short*)w; w += (long)LLAYERS * DFFN * DD * 2;
  unsigned short* W2T   = (unsigned short*)w; w += (long)LLAYERS * DD * DFFN * 2;
  unsigned short* teb   = (unsigned short*)w; w += (long)VV * DD * 2;

  prep_all_kernel<<<6144 + 16000 + NTOK, 256, 0, stream>>>(
      Wqkv, Wo, W1, W2, te, WqkvT, WoT, W1T, W2T, teb,
      ids, pe, Wr, br, res, probs, depth_ws, out_depth);
  router_finalize_kernel<<<1, 256, 0, stream>>>(probs, out_loss);

  for (int step = 0; step < RSTEPS; ++step) {
    for (int l = 0; l < LLAYERS; ++l) {
      const float* xin = (l == 0) ? res : x;
      ln_kernel<<<NTOK, 256, 0, stream>>>(xin, ln1g + l * DD, ln1b + l * DD, hbuf);
      gemm128_kernel<128, 1, 1, 0, 0, 1><<<dim3(3 * DD / 128, NTOK / 128), 256, 0, stream>>>(
          hbuf, DD, WqkvT + (long)l * 3 * DD * DD, DD, qkvb, 3 * DD,
          bqkv + (long)l * 3 * DD, nullptr, 0, vtb, DD);
      attn_kernel<<<dim3(SS / 128, BB * HH), 512, 0, stream>>>(qkvb, vtb, obuf);
      gemm64w8_kernel<0, 1, 1, 0><<<dim3(DD / 64, NTOK / 128), 512, 0, stream>>>(
          obuf, DD, WoT + (long)l * DD * DD, DD, x, DD,
          bo + (long)l * DD, xin, DD, nullptr, 0.f, DD);
      ln_kernel<<<NTOK, 256, 0, stream>>>(x, ln2g + l * DD, ln2b + l * DD, hbuf);
      gemm128_kernel<128, 1, 1, 0, 1, 0><<<dim3(DFFN / 128, NTOK / 128), 256, 0, stream>>>(
          hbuf, DD, W1T + (long)l * DFFN * DD, DD, ffn1, DFFN,
          b1 + (long)l * DFFN, nullptr, 0, nullptr, DD);
      if (l == 0) {
        gemm64w8_kernel<0, 1, 1, 0><<<dim3(DD / 64, NTOK / 128), 512, 0, stream>>>(
            ffn1, DFFN, W2T + (long)l * DD * DFFN, DFFN, x, DD,
            b2 + (long)l * DD, x, DD, nullptr, 0.f, DFFN);
      } else {
        gemm64w8_kernel<0, 1, 1, 1><<<dim3(DD / 64, NTOK / 128), 512, 0, stream>>>(
            ffn1, DFFN, W2T + (long)l * DD * DFFN, DFFN, res, DD,
            b2 + (long)l * DD, x, DD, depth_ws, (float)(step + 1), DFFN);
      }
    }
  }
  ln_kernel<<<NTOK, 256, 0, stream>>>(res, fing, finb, hbuf);
  gemm256_kernel<0, 0, 0><<<dim3(VV / 256, NTOK / 256), 512, 0, stream>>>(
      hbuf, DD, teb, DD, logits, VV, nullptr, DD, NTOK / 256);
}

// Round 12
// 1214.097 us; speedup vs baseline: 1.2056x; 1.1227x over previous
//
#include <hip/hip_runtime.h>
#include <hip/hip_bf16.h>

#define DD 1024
#define SS 1024
#define BB 2
#define HH 16
#define DFFN 4096
#define LLAYERS 2
#define RSTEPS 3
#define VV 32000
#define NTOK (BB*SS)

typedef __attribute__((ext_vector_type(8))) short s16x8;
typedef __attribute__((ext_vector_type(8))) __bf16 bf16x8;
typedef __attribute__((ext_vector_type(4))) float f32x4;

__device__ __forceinline__ unsigned short f2bf(float f) {
  unsigned int u = __float_as_uint(f);
  u += 0x7FFFu + ((u >> 16) & 1u);
  return (unsigned short)(u >> 16);
}

__device__ __forceinline__ f32x4 mfma16(s16x8 a, s16x8 b, f32x4 c) {
  return __builtin_amdgcn_mfma_f32_16x16x32_bf16(
      __builtin_bit_cast(bf16x8, a), __builtin_bit_cast(bf16x8, b), c, 0, 0, 0);
}

__device__ __forceinline__ void gload16(const unsigned short* g, unsigned short* l) {
  __builtin_amdgcn_global_load_lds(
      (const __attribute__((address_space(1))) unsigned int*)(const void*)g,
      (__attribute__((address_space(3))) unsigned int*)(void*)l, 16, 0, 0);
}

#define BAR()  asm volatile("s_barrier" ::: "memory")
#define LGK0() do { asm volatile("s_waitcnt lgkmcnt(0)" ::: "memory"); \
                    __builtin_amdgcn_sched_barrier(0); } while (0)
#define VM4()  asm volatile("s_waitcnt vmcnt(4)" ::: "memory")
#define VM0()  asm volatile("s_waitcnt vmcnt(0)" ::: "memory")

template<int N> __device__ __forceinline__ void vmw() {
  if constexpr (N == 0) asm volatile("s_waitcnt vmcnt(0)" ::: "memory");
  else if constexpr (N == 3) asm volatile("s_waitcnt vmcnt(3)" ::: "memory");
  else if constexpr (N == 4) asm volatile("s_waitcnt vmcnt(4)" ::: "memory");
  else if constexpr (N == 6) asm volatile("s_waitcnt vmcnt(6)" ::: "memory");
  else if constexpr (N == 8) asm volatile("s_waitcnt vmcnt(8)" ::: "memory");
}

// --- prep: weight transpose f32->bf16 [N][K], te conv, embed+router --------
__global__ __launch_bounds__(256) void prep_all_kernel(
    const float* __restrict__ Wqkv, const float* __restrict__ Wo,
    const float* __restrict__ W1, const float* __restrict__ W2,
    const float* __restrict__ te,
    unsigned short* __restrict__ WqkvT, unsigned short* __restrict__ WoT,
    unsigned short* __restrict__ W1T, unsigned short* __restrict__ W2T,
    unsigned short* __restrict__ teb,
    const int* __restrict__ ids, const float* __restrict__ pe,
    const float* __restrict__ Wr, const float* __restrict__ br,
    float* __restrict__ res, float* __restrict__ probs,
    float* __restrict__ depth_ws, float* __restrict__ out_depth) {
  const int bid = blockIdx.x;
  const int tid = threadIdx.x;
  __shared__ unsigned short t[64][68];
  __shared__ float red[4][3];
  if (bid >= 22144) {
    int row = bid - 22144;
    int s = row & (SS - 1);
    int id = ids[row];
    int d = tid * 4;
    float4 a = *(const float4*)(te + (long)id * DD + d);
    float4 p = *(const float4*)(pe + (long)s * DD + d);
    float4 o; o.x = a.x + p.x; o.y = a.y + p.y; o.z = a.z + p.z; o.w = a.w + p.w;
    *(float4*)(res + (long)row * DD + d) = o;
    float a0 = 0.f, a1 = 0.f, a2 = 0.f;
    float hv[4] = {o.x, o.y, o.z, o.w};
#pragma unroll
    for (int j = 0; j < 4; ++j) {
      int dd = d + j;
      a0 += hv[j] * Wr[dd * 3 + 0];
      a1 += hv[j] * Wr[dd * 3 + 1];
      a2 += hv[j] * Wr[dd * 3 + 2];
    }
    for (int off = 32; off; off >>= 1) {
      a0 += __shfl_down(a0, off);
      a1 += __shfl_down(a1, off);
      a2 += __shfl_down(a2, off);
    }
    int wave = tid >> 6;
    if ((tid & 63) == 0) { red[wave][0] = a0; red[wave][1] = a1; red[wave][2] = a2; }
    __syncthreads();
    if (tid == 0) {
      a0 = red[0][0] + red[1][0] + red[2][0] + red[3][0] + br[0];
      a1 = red[0][1] + red[1][1] + red[2][1] + red[3][1] + br[1];
      a2 = red[0][2] + red[1][2] + red[2][2] + red[3][2] + br[2];
      float m = fmaxf(a0, fmaxf(a1, a2));
      float e0 = expf(a0 - m), e1 = expf(a1 - m), e2 = expf(a2 - m);
      float inv = 1.f / (e0 + e1 + e2);
      probs[row * 3 + 0] = e0 * inv;
      probs[row * 3 + 1] = e1 * inv;
      probs[row * 3 + 2] = e2 * inv;
      int am = 0; float bv = a0;
      if (a1 > bv) { bv = a1; am = 1; }
      if (a2 > bv) { bv = a2; am = 2; }
      float dm = (float)(am + 1);
      depth_ws[row] = dm;
      out_depth[row] = dm;
    }
    return;
  }
  if (bid >= 6144) {
    long i = ((long)(bid - 6144) * 256 + tid) * 8;
    float4 v0 = *(const float4*)(te + i);
    float4 v1 = *(const float4*)(te + i + 4);
    ushort4 a, b;
    a.x = f2bf(v0.x); a.y = f2bf(v0.y); a.z = f2bf(v0.z); a.w = f2bf(v0.w);
    b.x = f2bf(v1.x); b.y = f2bf(v1.y); b.z = f2bf(v1.z); b.w = f2bf(v1.w);
    *(ushort4*)(teb + i) = a;
    *(ushort4*)(teb + i + 4) = b;
    return;
  }
  const float* src; unsigned short* dst; int Kd, Nd, local;
  if (bid < 1536) {
    int l = (bid >= 768);
    local = bid - l * 768;
    src = Wqkv + (long)l * DD * 3 * DD; dst = WqkvT + (long)l * 3 * DD * DD;
    Kd = DD; Nd = 3 * DD;
  } else if (bid < 2048) {
    int l = (bid - 1536) >> 8; local = (bid - 1536) & 255;
    src = Wo + (long)l * DD * DD; dst = WoT + (long)l * DD * DD;
    Kd = DD; Nd = DD;
  } else if (bid < 4096) {
    int l = (bid - 2048) >> 10; local = (bid - 2048) & 1023;
    src = W1 + (long)l * DD * DFFN; dst = W1T + (long)l * DFFN * DD;
    Kd = DD; Nd = DFFN;
  } else {
    int l = (bid - 4096) >> 10; local = (bid - 4096) & 1023;
    src = W2 + (long)l * DFFN * DD; dst = W2T + (long)l * DD * DFFN;
    Kd = DFFN; Nd = DD;
  }
  const int tn = Nd >> 6;
  const int n0 = (local % tn) * 64, k0 = (local / tn) * 64;
#pragma unroll
  for (int c = 0; c < 4; ++c) {
    int p = tid + c * 256;
    int kr = p >> 4, nc = (p & 15) * 4;
    float4 v = *(const float4*)(src + (long)(k0 + kr) * Nd + n0 + nc);
    t[nc + 0][kr] = f2bf(v.x);
    t[nc + 1][kr] = f2bf(v.y);
    t[nc + 2][kr] = f2bf(v.z);
    t[nc + 3][kr] = f2bf(v.w);
  }
  __syncthreads();
#pragma unroll
  for (int c = 0; c < 4; ++c) {
    int p = tid + c * 256;
    int nr = p >> 4, kc = (p & 15) * 4;
    ushort4 o;
    o.x = t[nr][kc]; o.y = t[nr][kc + 1]; o.z = t[nr][kc + 2]; o.w = t[nr][kc + 3];
    *(ushort4*)(dst + (long)(n0 + nr) * Kd + k0 + kc) = o;
  }
}

__global__ __launch_bounds__(256) void router_finalize_kernel(
    const float* __restrict__ probs, float* __restrict__ out_loss) {
  __shared__ float red[256][3];
  int t = threadIdx.x;
  float s0 = 0.f, s1 = 0.f, s2 = 0.f;
  for (int r = t; r < NTOK; r += 256) {
    s0 += probs[r * 3 + 0]; s1 += probs[r * 3 + 1]; s2 += probs[r * 3 + 2];
  }
  red[t][0] = s0; red[t][1] = s1; red[t][2] = s2;
  __syncthreads();
  for (int off = 128; off; off >>= 1) {
    if (t < off) {
      red[t][0] += red[t + off][0];
      red[t][1] += red[t + off][1];
      red[t][2] += red[t + off][2];
    }
    __syncthreads();
  }
  if (t == 0) {
    float i0 = red[0][0] / NTOK, i1 = red[0][1] / NTOK, i2 = red[0][2] / NTOK;
    out_loss[0] = (float)RSTEPS * (i0 * i0 + i1 * i1 + i2 * i2);
  }
}

// ---------------- layernorm: f32 in -> bf16 out ----------------------------
__global__ __launch_bounds__(256) void ln_kernel(
    const float* __restrict__ x, const float* __restrict__ g,
    const float* __restrict__ b, unsigned short* __restrict__ y) {
  int row = blockIdx.x;
  int t = threadIdx.x;
  float4 v = *(const float4*)(x + (long)row * DD + t * 4);
  float s = v.x + v.y + v.z + v.w;
  float q = v.x * v.x + v.y * v.y + v.z * v.z + v.w * v.w;
  for (int off = 32; off; off >>= 1) {
    s += __shfl_down(s, off);
    q += __shfl_down(q, off);
  }
  __shared__ float rs[4], rq[4];
  int wave = t >> 6;
  if ((t & 63) == 0) { rs[wave] = s; rq[wave] = q; }
  __syncthreads();
  float S_ = rs[0] + rs[1] + rs[2] + rs[3];
  float Q_ = rq[0] + rq[1] + rq[2] + rq[3];
  float mu = S_ * (1.f / DD);
  float var = Q_ * (1.f / DD) - mu * mu;
  float rstd = rsqrtf(var + 1e-5f);
  int d = t * 4;
  float4 gg = *(const float4*)(g + d);
  float4 bb = *(const float4*)(b + d);
  ushort4 ov;
  ov.x = f2bf((v.x - mu) * rstd * gg.x + bb.x);
  ov.y = f2bf((v.y - mu) * rstd * gg.y + bb.y);
  ov.z = f2bf((v.z - mu) * rstd * gg.z + bb.z);
  ov.w = f2bf((v.w - mu) * rstd * gg.w + bb.w);
  *(ushort4*)(y + (long)row * DD + d) = ov;
}

// ================= 256x256 8-phase GEMM (T2+T3+T4+T5) ======================
__device__ __forceinline__ void stageA8(unsigned short* S, int buf, int qm,
    const unsigned short* A, int lda, long m0, int kt, int tid) {
  unsigned short* dst = S + buf * 32768 + qm * 8192;
#pragma unroll
  for (int c = 0; c < 2; ++c) {
    int idx = tid + c * 512;
    int L = (idx << 4) ^ (((idx >> 5) & 1) << 5);
    int band = L >> 13, row = (L >> 7) & 63, kel = (L & 127) >> 1;
    gload16(A + (m0 + band * 128 + qm * 64 + row) * (long)lda + kt * 64 + kel,
            dst + idx * 8);
  }
}

__device__ __forceinline__ void stageB8(unsigned short* S, int buf, int qn,
    const unsigned short* Bt, int ldb, long n0, int kt, int tid) {
  unsigned short* dst = S + buf * 32768 + 16384 + qn * 8192;
#pragma unroll
  for (int c = 0; c < 2; ++c) {
    int idx = tid + c * 512;
    int L = (idx << 4) ^ (((idx >> 5) & 1) << 5);
    int band = L >> 12, row = (L >> 7) & 31, kel = (L & 127) >> 1;
    gload16(Bt + (n0 + band * 64 + qn * 32 + row) * (long)ldb + kt * 64 + kel,
            dst + idx * 8);
  }
}

__device__ __forceinline__ void read_af8(const unsigned short* S, int base,
    int wm, int l16, int g, s16x8 af[2][4]) {
  const int swz = ((l16 >> 2) & 1) << 5;
#pragma unroll
  for (int kk = 0; kk < 2; ++kk)
#pragma unroll
    for (int mf = 0; mf < 4; ++mf) {
      int L = (wm * 8192 + (mf * 16 + l16) * 128 + (kk * 32 + g * 8) * 2) ^ swz;
      af[kk][mf] = *(const s16x8*)(S + base + (L >> 1));
    }
}

__device__ __forceinline__ void read_bf8(const unsigned short* S, int base,
    int wn, int l16, int g, s16x8 bf[2][2]) {
  const int swz = ((l16 >> 2) & 1) << 5;
#pragma unroll
  for (int kk = 0; kk < 2; ++kk)
#pragma unroll
    for (int nf = 0; nf < 2; ++nf) {
      int L = (wn * 4096 + (nf * 16 + l16) * 128 + (kk * 32 + g * 8) * 2) ^ swz;
      bf[kk][nf] = *(const s16x8*)(S + base + (L >> 1));
    }
}

template<int QM, int QN>
__device__ __forceinline__ void do_mfma8(f32x4 acc[8][4],
    const s16x8 af[2][4], const s16x8 bf[2][2]) {
  __builtin_amdgcn_s_setprio(1);
#pragma unroll
  for (int kk = 0; kk < 2; ++kk)
#pragma unroll
    for (int mf = 0; mf < 4; ++mf)
#pragma unroll
      for (int nf = 0; nf < 2; ++nf)
        acc[QM * 4 + mf][QN * 2 + nf] =
            mfma16(af[kk][mf], bf[kk][nf], acc[QM * 4 + mf][QN * 2 + nf]);
  __builtin_amdgcn_s_setprio(0);
}

template<int CBF16, int BIAS, int GELU_ACT>
__global__ __launch_bounds__(512, 1) void gemm256_kernel(
    const unsigned short* __restrict__ A, int lda,
    const unsigned short* __restrict__ Bt, int ldb,
    void* __restrict__ Cv, int ldc,
    const float* __restrict__ bias, int K, int Mblocks) {
  __shared__ unsigned short S[65536];
  const int tid = threadIdx.x;
  const int lane = tid & 63, wave = tid >> 6;
  const int g = lane >> 4, l16 = lane & 15;
  const int wm = wave >> 2, wn = wave & 3;
  const int nwg = gridDim.x * gridDim.y;
  const int orig = blockIdx.x + blockIdx.y * gridDim.x;
  const int q = nwg >> 3, r = nwg & 7;
  const int xcd = orig & 7, loc = orig >> 3;
  const int wgid = (xcd < r ? xcd * (q + 1) : r * (q + 1) + (xcd - r) * q) + loc;
  const long m0 = (long)(wgid % Mblocks) * 256;
  const long n0 = (long)(wgid / Mblocks) * 256;

  f32x4 acc[8][4] = {};
  s16x8 af[2][4], bf[2][2];
  const int NI = K >> 7;

  stageA8(S, 0, 0, A, lda, m0, 0, tid);
  stageA8(S, 0, 1, A, lda, m0, 0, tid);
  stageB8(S, 0, 0, Bt, ldb, n0, 0, tid);
  stageB8(S, 0, 1, Bt, ldb, n0, 0, tid);
  stageA8(S, 1, 0, A, lda, m0, 1, tid);
  stageB8(S, 1, 1, Bt, ldb, n0, 1, tid);
  VM4(); BAR();

  for (int i = 0; i < NI; ++i) {
    const int kt1 = 2 * i + 1, kt2 = 2 * i + 2, kt3 = 2 * i + 3;
    const bool more = (i + 1 < NI);
    read_af8(S, 0, wm, l16, g, af);
    read_bf8(S, 16384, wn, l16, g, bf);
    stageA8(S, 1, 1, A, lda, m0, kt1, tid);
    BAR(); LGK0();
    do_mfma8<0, 0>(acc, af, bf);
    BAR();
    read_bf8(S, 16384 + 8192, wn, l16, g, bf);
    stageB8(S, 1, 0, Bt, ldb, n0, kt1, tid);
    BAR(); LGK0();
    do_mfma8<0, 1>(acc, af, bf);
    BAR();
    read_af8(S, 8192, wm, l16, g, af);
    if (more) stageA8(S, 0, 0, A, lda, m0, kt2, tid);
    BAR(); LGK0();
    do_mfma8<1, 1>(acc, af, bf);
    BAR();
    read_bf8(S, 16384, wn, l16, g, bf);
    if (more) stageB8(S, 0, 1, Bt, ldb, n0, kt2, tid);
    BAR(); LGK0();
    do_mfma8<1, 0>(acc, af, bf);
    if (more) { VM4(); } else { VM0(); }
    BAR();
    read_af8(S, 32768, wm, l16, g, af);
    read_bf8(S, 32768 + 16384, wn, l16, g, bf);
    if (more) stageA8(S, 0, 1, A, lda, m0, kt2, tid);
    BAR(); LGK0();
    do_mfma8<0, 0>(acc, af, bf);
    BAR();
    read_bf8(S, 32768 + 16384 + 8192, wn, l16, g, bf);
    if (more) stageB8(S, 0, 0, Bt, ldb, n0, kt2, tid);
    BAR(); LGK0();
    do_mfma8<0, 1>(acc, af, bf);
    BAR();
    read_af8(S, 32768 + 8192, wm, l16, g, af);
    if (more) stageA8(S, 1, 0, A, lda, m0, kt3, tid);
    BAR(); LGK0();
    do_mfma8<1, 1>(acc, af, bf);
    BAR();
    read_bf8(S, 32768 + 16384, wn, l16, g, bf);
    if (more) stageB8(S, 1, 1, Bt, ldb, n0, kt3, tid);
    BAR(); LGK0();
    do_mfma8<1, 0>(acc, af, bf);
    VM4(); BAR();
  }

#pragma unroll
  for (int mf = 0; mf < 8; ++mf) {
#pragma unroll
    for (int nf = 0; nf < 4; ++nf) {
      long row0 = m0 + wm * 128 + mf * 16 + g * 4;
      long col = n0 + wn * 64 + nf * 16 + l16;
      float bv = BIAS ? bias[col] : 0.f;
#pragma unroll
      for (int rr = 0; rr < 4; ++rr) {
        float v = acc[mf][nf][rr] + bv;
        if (GELU_ACT) {
          float x3 = v * v * v;
          v = 0.5f * v * (1.f + tanhf(0.7978845608028654f * (v + 0.044715f * x3)));
        }
        if (CBF16) ((unsigned short*)Cv)[(row0 + rr) * (long)ldc + col] = f2bf(v);
        else       ((float*)Cv)[(row0 + rr) * (long)ldc + col] = v;
      }
    }
  }
}

// ====== unified 512-thread dbuf GEMM: BM=128, BN in {64,128}, DEPTH 2/3 ====
// st_16x32 LDS swizzle (pre-swizzled global source + XOR'd read, as gemm256).
// 8 waves: wr=wave>>1 (4 row-bands of 32), wc=wave&1 (2 col-bands of BN/2).
// QKVW: Q/K cols -> Cv, V cols (>=2048) -> vtw transposed [BH][64][S].
template<int BN, int DEPTH, int CBF16, int BIAS, int RESID, int GELU_ACT,
         int SELW, int QKVW>
__global__ __launch_bounds__(512) void gemm_db_kernel(
    const unsigned short* __restrict__ A, int lda,
    const unsigned short* __restrict__ Bt, int ldb,
    void* __restrict__ Cv, int ldc,
    const float* __restrict__ bias,
    const float* __restrict__ resid, int ldr,
    const float* __restrict__ depth_ws, float stepf,
    unsigned short* __restrict__ vtw,
    int K) {
  constexpr int WN = BN / 2;
  constexpr int NR = WN / 16;
  constexpr int ACH = 2;            // A chunks of 512
  constexpr int BCH = BN / 64;      // B chunks of 512
  constexpr int LPT = ACH + BCH;    // loads/thread/tile
  __shared__ unsigned short As[DEPTH][128 * 64];
  __shared__ unsigned short Bs[DEPTH][BN * 64];
  const int tid = threadIdx.x;
  const int lane = tid & 63, wave = tid >> 6;
  const int g = lane >> 4, l16 = lane & 15;
  const int wr = wave >> 1, wc = wave & 1;
  int lin = blockIdx.x + blockIdx.y * gridDim.x;
  int per = (gridDim.x * gridDim.y) >> 3;
  int v = (lin & 7) * per + (lin >> 3);
  const long m0 = (long)(v % gridDim.y) * 128;
  const long n0 = (long)(v / gridDim.y) * BN;
  f32x4 acc[2][NR] = {};
  const int NT = K >> 6;

  auto stage = [&](int buf, int kt) {
    const int k0 = kt * 64;
#pragma unroll
    for (int c = 0; c < ACH; ++c) {
      int p = tid + c * 512;
      int L = (p << 4) ^ (((p >> 5) & 1) << 5);
      int row = L >> 7, kel = (L & 127) >> 1;
      gload16(A + (m0 + row) * (long)lda + k0 + kel, &As[buf][p * 8]);
    }
#pragma unroll
    for (int c = 0; c < BCH; ++c) {
      int p = tid + c * 512;
      int L = (p << 4) ^ (((p >> 5) & 1) << 5);
      int row = L >> 7, kel = (L & 127) >> 1;
      gload16(Bt + (n0 + row) * (long)ldb + k0 + kel, &Bs[buf][p * 8]);
    }
  };

#pragma unroll
  for (int j = 0; j < DEPTH - 1; ++j) stage(j, j);

  int cur = 0;
  const int swz = ((l16 >> 2) & 1) << 5;
  for (int kt = 0; kt < NT; ++kt) {
    const int rem = NT - 1 - kt;
    if (rem >= DEPTH - 1) {
      int tgt = cur + DEPTH - 1; if (tgt >= DEPTH) tgt -= DEPTH;
      stage(tgt, kt + DEPTH - 1);
      vmw<(DEPTH - 1) * LPT>();
    } else if (DEPTH == 3 && rem == 1) {
      vmw<LPT>();
    } else {
      vmw<0>();
    }
    BAR();
#pragma unroll
    for (int kk = 0; kk < 2; ++kk) {
      s16x8 af[2], bf[NR];
#pragma unroll
      for (int m = 0; m < 2; ++m) {
        int L = (((wr * 32 + m * 16 + l16) << 7) + ((kk * 32 + g * 8) << 1)) ^ swz;
        af[m] = *(const s16x8*)&As[cur][L >> 1];
      }
#pragma unroll
      for (int n = 0; n < NR; ++n) {
        int L = (((wc * WN + n * 16 + l16) << 7) + ((kk * 32 + g * 8) << 1)) ^ swz;
        bf[n] = *(const s16x8*)&Bs[cur][L >> 1];
      }
#pragma unroll
      for (int m = 0; m < 2; ++m)
#pragma unroll
        for (int n = 0; n < NR; ++n)
          acc[m][n] = mfma16(af[m], bf[n], acc[m][n]);
    }
    BAR();
    ++cur; if (cur == DEPTH) cur = 0;
  }

  const bool vblk = QKVW && (n0 >= 2048);
#pragma unroll
  for (int m = 0; m < 2; ++m) {
#pragma unroll
    for (int n = 0; n < NR; ++n) {
      long row_base = m0 + wr * 32 + m * 16 + g * 4;
      long col = n0 + wc * WN + n * 16 + l16;
      float bv = BIAS ? bias[col] : 0.f;
      float vv4[4];
#pragma unroll
      for (int r = 0; r < 4; ++r) {
        long row = row_base + r;
        float vv = acc[m][n][r] + bv;
        if (RESID) vv += resid[row * (long)ldr + col];
        if (GELU_ACT) {
          float x3 = vv * vv * vv;
          vv = 0.5f * vv * (1.f + tanhf(0.7978845608028654f * (vv + 0.044715f * x3)));
        }
        vv4[r] = vv;
      }
      if (QKVW && vblk) {
        int rel = (int)col - 2048;
        int h = rel >> 6, d = rel & 63;
        int b = (int)(row_base >> 10);
        int s = (int)(row_base & 1023);
        ushort4 o;
        o.x = f2bf(vv4[0]); o.y = f2bf(vv4[1]);
        o.z = f2bf(vv4[2]); o.w = f2bf(vv4[3]);
        *(ushort4*)(vtw + (((long)(b * 16 + h) * 64 + d) * SS + s)) = o;
      } else {
#pragma unroll
        for (int r = 0; r < 4; ++r) {
          long row = row_base + r;
          if (SELW) {
            if (depth_ws[row] >= stepf)
              ((float*)Cv)[row * (long)ldc + col] = vv4[r];
          } else if (CBF16) {
            ((unsigned short*)Cv)[row * (long)ldc + col] = f2bf(vv4[r]);
          } else {
            ((float*)Cv)[row * (long)ldc + col] = vv4[r];
          }
        }
      }
    }
  }
}

// -- flash attention: QBLK=128, 8 waves, swapped QK^T, dbuf, heavy-first ----
__global__ __launch_bounds__(512) void attn_kernel(
    const unsigned short* __restrict__ qkv,   // [NTOK][3072] (Q,K used)
    const unsigned short* __restrict__ vt,    // [BH][64][S]
    unsigned short* __restrict__ o) {         // [NTOK][1024]
  __shared__ unsigned short Ks[2][64 * 64];
  __shared__ unsigned short Vs[2][64 * 64];
  __shared__ unsigned short Pl[8][16][72];
  const int qb = gridDim.x - 1 - blockIdx.x;   // heavy (late-causal) blocks first
  const int bh = blockIdx.y;
  const int b = bh >> 4, h = bh & 15;
  const int tid = threadIdx.x, wave = tid >> 6, lane = tid & 63;
  const int g = lane >> 4, l16 = lane & 15;
  const float NEG_INF = -__builtin_inff();
  const int q0 = qb * 128;
  const int qrw = q0 + wave * 16;
  const long rowbase = (long)b * SS;
  const unsigned short* kbase = qkv + rowbase * 3072 + 1024 + h * 64;
  const unsigned short* vbase = vt + (long)bh * 64 * SS;

  const unsigned short* qptr = qkv + (rowbase + qrw + l16) * 3072 + h * 64;
  s16x8 qf0 = *(const s16x8*)(qptr + g * 8);
  s16x8 qf1 = *(const s16x8*)(qptr + 32 + g * 8);

  f32x4 oacc[4] = {};
  float mrun = NEG_INF, lrun = 0.f;

  const int ntile = q0 / 64 + 2;

  {
    int r = tid >> 3;
    int bo = (tid & 7) * 16;
    int sw = (bo ^ ((r & 7) << 4)) >> 1;
    gload16(kbase + (long)r * 3072 + sw, &Ks[0][tid * 8]);
    gload16(vbase + (long)r * SS + 0 + sw, &Vs[0][tid * 8]);
  }
  asm volatile("s_waitcnt vmcnt(0)" ::: "memory");
  __syncthreads();

  for (int t = 0; t < ntile; ++t) {
    const int cur = t & 1;
    const int kv0 = t * 64;
    const unsigned short* ks_cur = &Ks[cur][0];
    const unsigned short* vs_cur = &Vs[cur][0];
    if (t + 1 < ntile) {
      const int kvn = kv0 + 64;
      int r = tid >> 3;
      int bo = (tid & 7) * 16;
      int sw = (bo ^ ((r & 7) << 4)) >> 1;
      gload16(kbase + (long)(kvn + r) * 3072 + sw, &Ks[cur ^ 1][tid * 8]);
      gload16(vbase + (long)r * SS + kvn + sw, &Vs[cur ^ 1][tid * 8]);
    }
    f32x4 accs[4] = {};
#pragma unroll
    for (int ks = 0; ks < 2; ++ks) {
#pragma unroll
      for (int kvb = 0; kvb < 4; ++kvb) {
        int row = kvb * 16 + l16;
        int bo = ((ks * 64 + g * 16) ^ ((l16 & 7) << 4)) >> 1;
        s16x8 kf = *(const s16x8*)&ks_cur[row * 64 + bo];
        accs[kvb] = mfma16(kf, ks ? qf1 : qf0, accs[kvb]);
      }
    }
    const bool needmask = (kv0 + 63 > qrw);
    const int qabs = qrw + l16;
    float sv[4][4];
    float mloc = NEG_INF;
#pragma unroll
    for (int kvb = 0; kvb < 4; ++kvb) {
#pragma unroll
      for (int r = 0; r < 4; ++r) {
        float vv = accs[kvb][r] * 0.125f;
        if (needmask) {
          int kva = kv0 + kvb * 16 + g * 4 + r;
          if (kva > qabs) vv = NEG_INF;
        }
        sv[kvb][r] = vv;
        mloc = fmaxf(mloc, vv);
      }
    }
    mloc = fmaxf(mloc, __shfl_xor(mloc, 16));
    mloc = fmaxf(mloc, __shfl_xor(mloc, 32));
    float mnew = fmaxf(mrun, mloc);
    float alpha = __expf(mrun - mnew);
    float lsum = 0.f;
#pragma unroll
    for (int kvb = 0; kvb < 4; ++kvb) {
      float p0 = __expf(sv[kvb][0] - mnew);
      float p1 = __expf(sv[kvb][1] - mnew);
      float p2 = __expf(sv[kvb][2] - mnew);
      float p3 = __expf(sv[kvb][3] - mnew);
      lsum += (p0 + p1) + (p2 + p3);
      unsigned int w0 = (unsigned)f2bf(p0) | ((unsigned)f2bf(p1) << 16);
      unsigned int w1 = (unsigned)f2bf(p2) | ((unsigned)f2bf(p3) << 16);
      uint2 pw; pw.x = w0; pw.y = w1;
      *(uint2*)&Pl[wave][l16][kvb * 16 + g * 4] = pw;
    }
    lsum += __shfl_xor(lsum, 16);
    lsum += __shfl_xor(lsum, 32);
    lrun = lrun * alpha + lsum;
    mrun = mnew;
    float mult[4];
#pragma unroll
    for (int r = 0; r < 4; ++r) mult[r] = __shfl(alpha, g * 4 + r);
#pragma unroll
    for (int nd = 0; nd < 4; ++nd)
#pragma unroll
      for (int r = 0; r < 4; ++r) oacc[nd][r] *= mult[r];
#pragma unroll
    for (int kh = 0; kh < 2; ++kh) {
      s16x8 pa = *(const s16x8*)&Pl[wave][l16][kh * 32 + g * 8];
#pragma unroll
      for (int nd = 0; nd < 4; ++nd) {
        int row = nd * 16 + l16;
        int bo = ((kh * 64 + g * 16) ^ ((l16 & 7) << 4)) >> 1;
        s16x8 vf = *(const s16x8*)&vs_cur[row * 64 + bo];
        oacc[nd] = mfma16(pa, vf, oacc[nd]);
      }
    }
    asm volatile("s_waitcnt vmcnt(0)" ::: "memory");
    __syncthreads();
  }
  unsigned short* ob = o + (rowbase + qrw) * 1024 + h * 64;
#pragma unroll
  for (int r = 0; r < 4; ++r) {
    float lr = __shfl(lrun, g * 4 + r);
    float inv = 1.f / lr;
#pragma unroll
    for (int nd = 0; nd < 4; ++nd)
      ob[(long)(g * 4 + r) * 1024 + nd * 16 + l16] = f2bf(oacc[nd][r] * inv);
  }
}

extern "C" void kernel_launch(void* const* d_in, const int* in_sizes, int n_in,
                              void* d_out, int out_size, void* d_ws, size_t ws_size,
                              hipStream_t stream) {
  (void)in_sizes; (void)n_in; (void)out_size; (void)ws_size;
  const int*   ids  = (const int*)d_in[0];
  const float* te   = (const float*)d_in[1];
  const float* pe   = (const float*)d_in[2];
  const float* Wqkv = (const float*)d_in[3];
  const float* bqkv = (const float*)d_in[4];
  const float* Wo   = (const float*)d_in[5];
  const float* bo   = (const float*)d_in[6];
  const float* W1   = (const float*)d_in[7];
  const float* b1   = (const float*)d_in[8];
  const float* W2   = (const float*)d_in[9];
  const float* b2   = (const float*)d_in[10];
  const float* ln1g = (const float*)d_in[11];
  const float* ln1b = (const float*)d_in[12];
  const float* ln2g = (const float*)d_in[13];
  const float* ln2b = (const float*)d_in[14];
  const float* fing = (const float*)d_in[15];
  const float* finb = (const float*)d_in[16];
  const float* Wr   = (const float*)d_in[17];
  const float* br   = (const float*)d_in[18];

  float* logits    = (float*)d_out;
  float* out_depth = logits + (long)NTOK * VV;
  float* out_loss  = out_depth + NTOK;

  char* w = (char*)d_ws;
  float* res            = (float*)w;          w += (long)NTOK * DD * 4;
  float* x              = (float*)w;          w += (long)NTOK * DD * 4;
  unsigned short* hbuf  = (unsigned short*)w; w += (long)NTOK * DD * 2;
  unsigned short* qkvb  = (unsigned short*)w; w += (long)NTOK * 3 * DD * 2;
  unsigned short* obuf  = (unsigned short*)w; w += (long)NTOK * DD * 2;
  unsigned short* ffn1  = (unsigned short*)w; w += (long)NTOK * DFFN * 2;
  unsigned short* vtb   = (unsigned short*)w; w += (long)BB * HH * 64 * SS * 2;
  float* probs          = (float*)w;          w += (long)NTOK * 3 * 4;
  float* depth_ws       = (float*)w;          w += (long)NTOK * 4;
  unsigned short* WqkvT = (unsigned short*)w; w += (long)LLAYERS * 3 * DD * DD * 2;
  unsigned short* WoT   = (unsigned short*)w; w += (long)LLAYERS * DD * DD * 2;
  unsigned short* W1T   = (unsigned short*)w; w += (long)LLAYERS * DFFN * DD * 2;
  unsigned short* W2T   = (unsigned short*)w; w += (long)LLAYERS * DD * DFFN * 2;
  unsigned short* teb   = (unsigned short*)w; w += (long)VV * DD * 2;

  prep_all_kernel<<<6144 + 16000 + NTOK, 256, 0, stream>>>(
      Wqkv, Wo, W1, W2, te, WqkvT, WoT, W1T, W2T, teb,
      ids, pe, Wr, br, res, probs, depth_ws, out_depth);
  router_finalize_kernel<<<1, 256, 0, stream>>>(probs, out_loss);

  for (int step = 0; step < RSTEPS; ++step) {
    for (int l = 0; l < LLAYERS; ++l) {
      const float* xin = (l == 0) ? res : x;
      ln_kernel<<<NTOK, 256, 0, stream>>>(xin, ln1g + l * DD, ln1b + l * DD, hbuf);
      gemm_db_kernel<128, 2, 1, 1, 0, 0, 0, 1>
          <<<dim3(3 * DD / 128, NTOK / 128), 512, 0, stream>>>(
          hbuf, DD, WqkvT + (long)l * 3 * DD * DD, DD, qkvb, 3 * DD,
          bqkv + (long)l * 3 * DD, nullptr, 0, nullptr, 0.f, vtb, DD);
      attn_kernel<<<dim3(SS / 128, BB * HH), 512, 0, stream>>>(qkvb, vtb, obuf);
      gemm_db_kernel<64, 3, 0, 1, 1, 0, 0, 0>
          <<<dim3(DD / 64, NTOK / 128), 512, 0, stream>>>(
          obuf, DD, WoT + (long)l * DD * DD, DD, x, DD,
          bo + (long)l * DD, xin, DD, nullptr, 0.f, nullptr, DD);
      ln_kernel<<<NTOK, 256, 0, stream>>>(x, ln2g + l * DD, ln2b + l * DD, hbuf);
      gemm_db_kernel<128, 2, 1, 1, 0, 1, 0, 0>
          <<<dim3(DFFN / 128, NTOK / 128), 512, 0, stream>>>(
          hbuf, DD, W1T + (long)l * DFFN * DD, DD, ffn1, DFFN,
          b1 + (long)l * DFFN, nullptr, 0, nullptr, 0.f, nullptr, DD);
      if (l == 0) {
        gemm_db_kernel<64, 3, 0, 1, 1, 0, 0, 0>
            <<<dim3(DD / 64, NTOK / 128), 512, 0, stream>>>(
            ffn1, DFFN, W2T + (long)l * DD * DFFN, DFFN, x, DD,
            b2 + (long)l * DD, x, DD, nullptr, 0.f, nullptr, DFFN);
      } else {
        gemm_db_kernel<64, 3, 0, 1, 1, 0, 1, 0>
            <<<dim3(DD / 64, NTOK / 128), 512, 0, stream>>>(
            ffn1, DFFN, W2T + (long)l * DD * DFFN, DFFN, res, DD,
            b2 + (long)l * DD, x, DD, depth_ws, (float)(step + 1), nullptr, DFFN);
      }
    }
  }
  ln_kernel<<<NTOK, 256, 0, stream>>>(res, fing, finb, hbuf);
  gemm256_kernel<0, 0, 0><<<dim3(VV / 256, NTOK / 256), 512, 0, stream>>>(
      hbuf, DD, teb, DD, logits, VV, nullptr, DD, NTOK / 256);
}